// Round 1
// baseline (2543.911 us; speedup 1.0000x reference)
//
#include <hip/hip_runtime.h>

typedef short bf16x8 __attribute__((ext_vector_type(8)));
typedef float f32x4 __attribute__((ext_vector_type(4)));

constexpr int NN = 50000;   // nodes
constexpr int NG = 64;      // graphs
constexpr int MP = 50048;   // nodes padded to 128 (391*128)
constexpr int D0 = 900;     // input feature dim
constexpr int K0 = 928;     // conv1 K padded to 32
constexpr int D1 = 1024;    // conv1 out dim / conv2 K
constexpr int D2 = 2048;    // conv2 out dim

__device__ __forceinline__ float bf2f(unsigned short u) {
  return __uint_as_float(((unsigned)u) << 16);
}
__device__ __forceinline__ unsigned short f2bf(float f) {
  unsigned x = __float_as_uint(f);
  return (unsigned short)((x + 0x7fffu + ((x >> 16) & 1u)) >> 16);
}

__device__ __forceinline__ void gl_lds16(const void* g, void* l) {
  __builtin_amdgcn_global_load_lds((const __attribute__((address_space(1))) void*)g,
                                   (__attribute__((address_space(3))) void*)l, 16, 0, 0);
}

// ---------------- convert fp32 -> bf16 with zero padding ----------------
// grid = Rpad blocks; rows >= Rin and cols >= Cin are zero-filled.
__global__ void cvt_pad(const float* __restrict__ in, unsigned short* __restrict__ out,
                        int Rin, int Cin, int Cpad) {
  int r = blockIdx.x;
  const float* src = in + (size_t)r * Cin;
  unsigned short* dst = out + (size_t)r * Cpad;
  for (int c = threadIdx.x; c < Cpad; c += blockDim.x) {
    float v = (r < Rin && c < Cin) ? src[c] : 0.f;
    dst[c] = f2bf(v);
  }
}

// ---------------- CSR build ----------------
__global__ void zero_i(int* p, int n) {
  int i = blockIdx.x * blockDim.x + threadIdx.x;
  if (i < n) p[i] = 0;
}
__global__ void count_k(const int* __restrict__ dst, int* __restrict__ deg, int E, int n) {
  int e = blockIdx.x * blockDim.x + threadIdx.x;
  if (e < E) {
    int d = dst[e];
    if ((unsigned)d < (unsigned)n) atomicAdd(&deg[d], 1);
  }
}
// single-block exclusive scan, n <= 1024*64
__global__ void scan_k(const int* __restrict__ deg, int* __restrict__ off, int n) {
  __shared__ int s[1024];
  __shared__ int carry;
  int t = threadIdx.x;
  if (t == 0) carry = 0;
  __syncthreads();
  for (int base = 0; base < n; base += 1024) {
    int v = (base + t < n) ? deg[base + t] : 0;
    s[t] = v;
    __syncthreads();
    for (int d = 1; d < 1024; d <<= 1) {
      int x = (t >= d) ? s[t - d] : 0;
      __syncthreads();
      s[t] += x;
      __syncthreads();
    }
    if (base + t < n) off[base + t] = carry + s[t] - v;
    int total = s[1023];
    __syncthreads();
    if (t == 0) carry += total;
    __syncthreads();
  }
  if (t == 0) off[n] = carry;
}
__global__ void copy_i(const int* a, int* b, int n) {
  int i = blockIdx.x * blockDim.x + threadIdx.x;
  if (i < n) b[i] = a[i];
}
__global__ void fill_k(const int* __restrict__ src, const int* __restrict__ dst,
                       int* __restrict__ cursor, int* __restrict__ csr, int E, int n) {
  int e = blockIdx.x * blockDim.x + threadIdx.x;
  if (e < E) {
    int d = dst[e];
    if ((unsigned)d < (unsigned)n) {
      int p = atomicAdd(&cursor[d], 1);
      int s = src[e];
      if ((unsigned)s >= (unsigned)n) s = 0;  // defensive clamp
      csr[p] = s;
    }
  }
}

// ---------------- mean aggregation: block per node ----------------
// feat: bf16 [*, K]; out: bf16 [MP, K]. fp32 accumulate, 4 dims/thread.
__global__ __launch_bounds__(256) void agg_mean(const unsigned short* __restrict__ feat,
                                                const int* __restrict__ off,
                                                const int* __restrict__ csr,
                                                unsigned short* __restrict__ out, int K) {
  int node = blockIdx.x;
  int d = threadIdx.x * 4;
  if (d >= K) return;
  int e0 = off[node], e1 = off[node + 1];
  float a0 = 0.f, a1 = 0.f, a2 = 0.f, a3 = 0.f;
  for (int e = e0; e < e1; ++e) {
    int s = csr[e];
    ushort4 v = *(const ushort4*)&feat[(size_t)s * K + d];
    a0 += bf2f(v.x); a1 += bf2f(v.y); a2 += bf2f(v.z); a3 += bf2f(v.w);
  }
  int deg = e1 - e0;
  float inv = 1.f / (float)(deg > 1 ? deg : 1);
  ushort4 o;
  o.x = f2bf(a0 * inv); o.y = f2bf(a1 * inv); o.z = f2bf(a2 * inv); o.w = f2bf(a3 * inv);
  *(ushort4*)&out[(size_t)node * K + d] = o;
}

// ---------------- dual-operand bf16 MFMA GEMM ----------------
// C[m,n] = relu?( sum_k A1[m,k]W1[n,k] + sum_k A2[m,k]W2[n,k] + bias[n] ), bf16 out
// 128x128 tile, 4 waves each 64x64, 16x16x32 bf16 MFMA, global_load_lds staging.
template <int KP, int N, bool RELU>
__global__ __launch_bounds__(256) void gemm_dual(const unsigned short* __restrict__ A1,
                                                 const unsigned short* __restrict__ W1,
                                                 const unsigned short* __restrict__ A2,
                                                 const unsigned short* __restrict__ W2,
                                                 const float* __restrict__ bias,
                                                 unsigned short* __restrict__ C) {
  __shared__ unsigned short sA[128 * 32];
  __shared__ unsigned short sB[128 * 32];
  const int tid = threadIdx.x;
  const int wave = tid >> 6, lane = tid & 63;
  const int quad = lane >> 4, l16 = lane & 15;
  const int wm = (wave >> 1) * 64, wn = (wave & 1) * 64;
  const long long bm = (long long)blockIdx.y * 128;
  const long long bn = (long long)blockIdx.x * 128;

  const int srow = wave * 16 + (lane >> 2);   // staging row within 64-row half
  const int skoff = (lane & 3) * 8;           // staging k offset (elements)
  unsigned short* lA = &sA[wave * 512 + lane * 8];
  unsigned short* lB = &sB[wave * 512 + lane * 8];

  f32x4 acc[4][4];
#pragma unroll
  for (int i = 0; i < 4; ++i)
#pragma unroll
    for (int j = 0; j < 4; ++j) acc[i][j] = (f32x4){0.f, 0.f, 0.f, 0.f};

#pragma unroll 1
  for (int pass = 0; pass < 2; ++pass) {
    const unsigned short* A = pass ? A2 : A1;
    const unsigned short* W = pass ? W2 : W1;
    const unsigned short* gA = A + (bm + srow) * KP + skoff;
    const unsigned short* gW = W + (bn + srow) * KP + skoff;
#pragma unroll 1
    for (int k0 = 0; k0 < KP; k0 += 32) {
      __syncthreads();  // previous iteration's LDS reads complete
      gl_lds16(gA + k0, lA);
      gl_lds16(gA + k0 + 64 * KP, lA + 2048);
      gl_lds16(gW + k0, lB);
      gl_lds16(gW + k0 + 64 * KP, lB + 2048);
      __syncthreads();  // staging complete (vmcnt drained by barrier)
      bf16x8 af[4], bg[4];
#pragma unroll
      for (int i = 0; i < 4; ++i)
        af[i] = *(const bf16x8*)&sA[(wm + 16 * i + l16) * 32 + quad * 8];
#pragma unroll
      for (int j = 0; j < 4; ++j)
        bg[j] = *(const bf16x8*)&sB[(wn + 16 * j + l16) * 32 + quad * 8];
#pragma unroll
      for (int i = 0; i < 4; ++i)
#pragma unroll
        for (int j = 0; j < 4; ++j)
          acc[i][j] = __builtin_amdgcn_mfma_f32_16x16x32_bf16(af[i], bg[j], acc[i][j], 0, 0, 0);
    }
  }

#pragma unroll
  for (int j = 0; j < 4; ++j) {
    const long long col = bn + wn + 16 * j + l16;
    const float bv = bias[col];
#pragma unroll
    for (int i = 0; i < 4; ++i) {
      const long long row0 = bm + wm + 16 * i + quad * 4;
#pragma unroll
      for (int r = 0; r < 4; ++r) {
        float v = acc[i][j][r] + bv;
        if (RELU) v = fmaxf(v, 0.f);
        C[(row0 + r) * (long long)N + col] = f2bf(v);
      }
    }
  }
}

// ---------------- graph boundaries (batch is sorted) ----------------
__global__ void bounds_k(const int* __restrict__ batch, int* __restrict__ gstart, int n, int G) {
  int g = blockIdx.x * blockDim.x + threadIdx.x;
  if (g > G) return;
  int lo = 0, hi = n;
  while (lo < hi) {
    int mid = (lo + hi) >> 1;
    if (batch[mid] < g) lo = mid + 1; else hi = mid;
  }
  gstart[g] = lo;
}

// ---------------- segment max pool ----------------
__global__ void segmax_k(const unsigned short* __restrict__ h2b, const int* __restrict__ gstart,
                         float* __restrict__ pooled) {
  int g = blockIdx.x;
  int c = blockIdx.y * 256 + threadIdx.x;
  int i0 = gstart[g], i1 = gstart[g + 1];
  float m = -3.4e38f;
  for (int i = i0; i < i1; ++i) m = fmaxf(m, bf2f(h2b[(size_t)i * D2 + c]));
  if (i0 >= i1) m = 0.f;  // empty graph -> 0 (matches isfinite guard)
  pooled[(size_t)g * D2 + c] = m;
}

// ---------------- MLP head (fp32) ----------------
__global__ void head1_k(const float* __restrict__ pooled, const float* __restrict__ Wf1,
                        const float* __restrict__ bf1, float* __restrict__ hid) {
  int g = blockIdx.x, chunk = blockIdx.y;  // 16 chunks of 64 outputs
  __shared__ float sp[2048];
  for (int i = threadIdx.x; i < 2048; i += 256) sp[i] = pooled[(size_t)g * 2048 + i];
  __syncthreads();
  int wave = threadIdx.x >> 6, lane = threadIdx.x & 63;
  for (int oi = wave; oi < 64; oi += 4) {
    int o = chunk * 64 + oi;
    const float4* wr = (const float4*)&Wf1[(size_t)o * 2048];
    float s = 0.f;
    for (int c = lane; c < 512; c += 64) {
      float4 wv = wr[c];
      float4 pv = *(const float4*)&sp[c * 4];
      s += wv.x * pv.x + wv.y * pv.y + wv.z * pv.z + wv.w * pv.w;
    }
    for (int off = 32; off; off >>= 1) s += __shfl_down(s, off);
    if (lane == 0) hid[(size_t)g * 1024 + o] = fmaxf(s + bf1[o], 0.f);
  }
}
__global__ void head2_k(const float* __restrict__ hid, const float* __restrict__ Wf2,
                        const float* __restrict__ bf2, float* __restrict__ out) {
  int g = blockIdx.x, t = threadIdx.x;
  __shared__ float sh[1024];
  __shared__ float red[256];
  for (int i = t; i < 1024; i += 256) sh[i] = hid[(size_t)g * 1024 + i];
  __syncthreads();
  for (int o = 0; o < 6; ++o) {
    float s = 0.f;
    for (int k = t; k < 1024; k += 256) s += sh[k] * Wf2[o * 1024 + k];
    red[t] = s;
    __syncthreads();
    for (int d = 128; d; d >>= 1) {
      if (t < d) red[t] += red[t + d];
      __syncthreads();
    }
    if (t == 0) out[g * 6 + o] = red[0] + bf2[o];
    __syncthreads();
  }
}

extern "C" void kernel_launch(void* const* d_in, const int* in_sizes, int n_in,
                              void* d_out, int out_size, void* d_ws, size_t ws_size,
                              hipStream_t stream) {
  const float* x    = (const float*)d_in[0];
  const int* ei     = (const int*)d_in[1];
  const int* batch  = (const int*)d_in[2];
  const float* W1l  = (const float*)d_in[3];
  const float* b1   = (const float*)d_in[4];
  const float* W1r  = (const float*)d_in[5];
  const float* W2l  = (const float*)d_in[6];
  const float* b2   = (const float*)d_in[7];
  const float* W2r  = (const float*)d_in[8];
  const float* Wf1  = (const float*)d_in[9];
  const float* bf1  = (const float*)d_in[10];
  const float* Wf2  = (const float*)d_in[11];
  const float* bf2  = (const float*)d_in[12];
  float* out = (float*)d_out;

  const int E = in_sizes[1] / 2;
  const int* srcp = ei;
  const int* dstp = ei + E;

  char* w = (char*)d_ws;
  auto take = [&](size_t b) {
    void* p = (void*)w;
    w += (b + 255) & ~(size_t)255;
    return p;
  };
  unsigned short* xb     = (unsigned short*)take((size_t)MP * K0 * 2);
  unsigned short* meanb  = (unsigned short*)take((size_t)MP * K0 * 2);
  unsigned short* h1b    = (unsigned short*)take((size_t)MP * D1 * 2);
  unsigned short* mean2b = (unsigned short*)take((size_t)MP * D1 * 2);
  unsigned short* h2b    = (unsigned short*)take((size_t)MP * D2 * 2);
  unsigned short* w1lb   = (unsigned short*)take((size_t)D1 * K0 * 2);
  unsigned short* w1rb   = (unsigned short*)take((size_t)D1 * K0 * 2);
  unsigned short* w2lb   = (unsigned short*)take((size_t)D2 * D1 * 2);
  unsigned short* w2rb   = (unsigned short*)take((size_t)D2 * D1 * 2);
  int* deg    = (int*)take((size_t)MP * 4);
  int* off    = (int*)take((size_t)(MP + 1) * 4);
  int* cursor = (int*)take((size_t)MP * 4);
  int* csr    = (int*)take((size_t)E * 4);
  int* gstart = (int*)take((size_t)(NG + 1) * 4);
  float* pooled = (float*)take((size_t)NG * D2 * 4);
  float* hid    = (float*)take((size_t)NG * 1024 * 4);

  // bf16 conversions (with padding)
  cvt_pad<<<MP, 256, 0, stream>>>(x, xb, NN, D0, K0);
  cvt_pad<<<D1, 256, 0, stream>>>(W1l, w1lb, D1, D0, K0);
  cvt_pad<<<D1, 256, 0, stream>>>(W1r, w1rb, D1, D0, K0);
  cvt_pad<<<D2, 256, 0, stream>>>(W2l, w2lb, D2, D1, D1);
  cvt_pad<<<D2, 256, 0, stream>>>(W2r, w2rb, D2, D1, D1);

  // CSR by dst
  zero_i<<<(MP + 255) / 256, 256, 0, stream>>>(deg, MP);
  count_k<<<(E + 255) / 256, 256, 0, stream>>>(dstp, deg, E, NN);
  scan_k<<<1, 1024, 0, stream>>>(deg, off, MP);
  copy_i<<<(MP + 255) / 256, 256, 0, stream>>>(off, cursor, MP);
  fill_k<<<(E + 255) / 256, 256, 0, stream>>>(srcp, dstp, cursor, csr, E, NN);

  // conv1
  agg_mean<<<MP, 256, 0, stream>>>(xb, off, csr, meanb, K0);
  gemm_dual<K0, D1, true><<<dim3(D1 / 128, MP / 128), 256, 0, stream>>>(
      meanb, w1lb, xb, w1rb, b1, h1b);

  // conv2
  agg_mean<<<MP, 256, 0, stream>>>(h1b, off, csr, mean2b, D1);
  gemm_dual<D1, D2, false><<<dim3(D2 / 128, MP / 128), 256, 0, stream>>>(
      mean2b, w2lb, h1b, w2rb, b2, h2b);

  // pool + head
  bounds_k<<<1, 128, 0, stream>>>(batch, gstart, NN, NG);
  segmax_k<<<dim3(NG, D2 / 256), 256, 0, stream>>>(h2b, gstart, pooled);
  head1_k<<<dim3(NG, 16), 256, 0, stream>>>(pooled, Wf1, bf1, hid);
  head2_k<<<NG, 256, 0, stream>>>(hid, Wf2, bf2, out);
}

// Round 2
// 2543.826 us; speedup vs baseline: 1.0000x; 1.0000x over previous
//
#include <hip/hip_runtime.h>

typedef short bf16x8 __attribute__((ext_vector_type(8)));
typedef unsigned short u16x8 __attribute__((ext_vector_type(8)));
typedef float f32x4 __attribute__((ext_vector_type(4)));

constexpr int NN = 50000;   // nodes
constexpr int NG = 64;      // graphs
constexpr int MP = 50048;   // nodes padded to 128 (391*128)
constexpr int D0 = 900;     // input feature dim
constexpr int K0 = 928;     // conv1 K padded to 32
constexpr int D1 = 1024;    // conv1 out dim / conv2 K
constexpr int D2 = 2048;    // conv2 out dim

__device__ __forceinline__ float bf2f(unsigned short u) {
  return __uint_as_float(((unsigned)u) << 16);
}
__device__ __forceinline__ unsigned short f2bf(float f) {
  unsigned x = __float_as_uint(f);
  return (unsigned short)((x + 0x7fffu + ((x >> 16) & 1u)) >> 16);
}

__device__ __forceinline__ void gl_lds16(const void* g, void* l) {
  __builtin_amdgcn_global_load_lds((const __attribute__((address_space(1))) void*)g,
                                   (__attribute__((address_space(3))) void*)l, 16, 0, 0);
}

// ---------------- convert fp32 -> bf16 with zero padding ----------------
__global__ void cvt_pad(const float* __restrict__ in, unsigned short* __restrict__ out,
                        int Rin, int Cin, int Cpad) {
  int r = blockIdx.x;
  const float* src = in + (size_t)r * Cin;
  unsigned short* dst = out + (size_t)r * Cpad;
  for (int c = threadIdx.x; c < Cpad; c += blockDim.x) {
    float v = (r < Rin && c < Cin) ? src[c] : 0.f;
    dst[c] = f2bf(v);
  }
}

// ---------------- CSR build ----------------
__global__ void zero_i(int* p, int n) {
  int i = blockIdx.x * blockDim.x + threadIdx.x;
  if (i < n) p[i] = 0;
}
__global__ void count_k(const int* __restrict__ dst, int* __restrict__ deg, int E, int n) {
  int e = blockIdx.x * blockDim.x + threadIdx.x;
  if (e < E) {
    int d = dst[e];
    if ((unsigned)d < (unsigned)n) atomicAdd(&deg[d], 1);
  }
}
__global__ void scan_k(const int* __restrict__ deg, int* __restrict__ off, int n) {
  __shared__ int s[1024];
  __shared__ int carry;
  int t = threadIdx.x;
  if (t == 0) carry = 0;
  __syncthreads();
  for (int base = 0; base < n; base += 1024) {
    int v = (base + t < n) ? deg[base + t] : 0;
    s[t] = v;
    __syncthreads();
    for (int d = 1; d < 1024; d <<= 1) {
      int x = (t >= d) ? s[t - d] : 0;
      __syncthreads();
      s[t] += x;
      __syncthreads();
    }
    if (base + t < n) off[base + t] = carry + s[t] - v;
    int total = s[1023];
    __syncthreads();
    if (t == 0) carry += total;
    __syncthreads();
  }
  if (t == 0) off[n] = carry;
}
__global__ void copy_i(const int* a, int* b, int n) {
  int i = blockIdx.x * blockDim.x + threadIdx.x;
  if (i < n) b[i] = a[i];
}
__global__ void fill_k(const int* __restrict__ src, const int* __restrict__ dst,
                       int* __restrict__ cursor, int* __restrict__ csr, int E, int n) {
  int e = blockIdx.x * blockDim.x + threadIdx.x;
  if (e < E) {
    int d = dst[e];
    if ((unsigned)d < (unsigned)n) {
      int p = atomicAdd(&cursor[d], 1);
      int s = src[e];
      if ((unsigned)s >= (unsigned)n) s = 0;
      csr[p] = s;
    }
  }
}

// ---------------- mean aggregation, MLP-optimized ----------------
// Block = 1 node. Two half-blocks (128 threads) each process alternate edges,
// 16B (8 bf16) loads, 4-deep edge unroll -> up to 8 concurrent 16B gathers per
// half. fp32 accumulate; halves combined through LDS.
__global__ __launch_bounds__(256) void agg_mean(const unsigned short* __restrict__ feat,
                                                const int* __restrict__ off,
                                                const int* __restrict__ csr,
                                                unsigned short* __restrict__ out, int K) {
  __shared__ float red[128 * 8];
  const int node = blockIdx.x;
  const int half = threadIdx.x >> 7;   // 0/1
  const int lane = threadIdx.x & 127;
  const int d = lane * 8;
  const bool act = (d < K);

  const int e0 = off[node], e1 = off[node + 1];
  float a0 = 0.f, a1 = 0.f, a2 = 0.f, a3 = 0.f, a4 = 0.f, a5 = 0.f, a6 = 0.f, a7 = 0.f;

  if (act) {
    int e = e0 + half;
    // 4 edges (of this half's stride-2 sequence) in flight
    for (; e + 6 < e1; e += 8) {
      int s0 = csr[e], s1 = csr[e + 2], s2 = csr[e + 4], s3 = csr[e + 6];
      u16x8 v0 = *(const u16x8*)&feat[(size_t)s0 * K + d];
      u16x8 v1 = *(const u16x8*)&feat[(size_t)s1 * K + d];
      u16x8 v2 = *(const u16x8*)&feat[(size_t)s2 * K + d];
      u16x8 v3 = *(const u16x8*)&feat[(size_t)s3 * K + d];
      a0 += bf2f(v0[0]) + bf2f(v1[0]) + bf2f(v2[0]) + bf2f(v3[0]);
      a1 += bf2f(v0[1]) + bf2f(v1[1]) + bf2f(v2[1]) + bf2f(v3[1]);
      a2 += bf2f(v0[2]) + bf2f(v1[2]) + bf2f(v2[2]) + bf2f(v3[2]);
      a3 += bf2f(v0[3]) + bf2f(v1[3]) + bf2f(v2[3]) + bf2f(v3[3]);
      a4 += bf2f(v0[4]) + bf2f(v1[4]) + bf2f(v2[4]) + bf2f(v3[4]);
      a5 += bf2f(v0[5]) + bf2f(v1[5]) + bf2f(v2[5]) + bf2f(v3[5]);
      a6 += bf2f(v0[6]) + bf2f(v1[6]) + bf2f(v2[6]) + bf2f(v3[6]);
      a7 += bf2f(v0[7]) + bf2f(v1[7]) + bf2f(v2[7]) + bf2f(v3[7]);
    }
    for (; e < e1; e += 2) {
      int s = csr[e];
      u16x8 v = *(const u16x8*)&feat[(size_t)s * K + d];
      a0 += bf2f(v[0]); a1 += bf2f(v[1]); a2 += bf2f(v[2]); a3 += bf2f(v[3]);
      a4 += bf2f(v[4]); a5 += bf2f(v[5]); a6 += bf2f(v[6]); a7 += bf2f(v[7]);
    }
  }
  if (half == 1 && act) {
    float* r = &red[lane * 8];
    r[0] = a0; r[1] = a1; r[2] = a2; r[3] = a3;
    r[4] = a4; r[5] = a5; r[6] = a6; r[7] = a7;
  }
  __syncthreads();
  if (half == 0 && act) {
    const float* r = &red[lane * 8];
    int deg = e1 - e0;
    float inv = 1.f / (float)(deg > 1 ? deg : 1);
    u16x8 o;
    o[0] = f2bf((a0 + r[0]) * inv); o[1] = f2bf((a1 + r[1]) * inv);
    o[2] = f2bf((a2 + r[2]) * inv); o[3] = f2bf((a3 + r[3]) * inv);
    o[4] = f2bf((a4 + r[4]) * inv); o[5] = f2bf((a5 + r[5]) * inv);
    o[6] = f2bf((a6 + r[6]) * inv); o[7] = f2bf((a7 + r[7]) * inv);
    *(u16x8*)&out[(size_t)node * K + d] = o;
  }
}

// ---------------- dual-operand bf16 MFMA GEMM ----------------
template <int KP, int N, bool RELU>
__global__ __launch_bounds__(256) void gemm_dual(const unsigned short* __restrict__ A1,
                                                 const unsigned short* __restrict__ W1,
                                                 const unsigned short* __restrict__ A2,
                                                 const unsigned short* __restrict__ W2,
                                                 const float* __restrict__ bias,
                                                 unsigned short* __restrict__ C) {
  __shared__ unsigned short sA[128 * 32];
  __shared__ unsigned short sB[128 * 32];
  const int tid = threadIdx.x;
  const int wave = tid >> 6, lane = tid & 63;
  const int quad = lane >> 4, l16 = lane & 15;
  const int wm = (wave >> 1) * 64, wn = (wave & 1) * 64;
  const long long bm = (long long)blockIdx.y * 128;
  const long long bn = (long long)blockIdx.x * 128;

  const int srow = wave * 16 + (lane >> 2);
  const int skoff = (lane & 3) * 8;
  unsigned short* lA = &sA[wave * 512 + lane * 8];
  unsigned short* lB = &sB[wave * 512 + lane * 8];

  f32x4 acc[4][4];
#pragma unroll
  for (int i = 0; i < 4; ++i)
#pragma unroll
    for (int j = 0; j < 4; ++j) acc[i][j] = (f32x4){0.f, 0.f, 0.f, 0.f};

#pragma unroll 1
  for (int pass = 0; pass < 2; ++pass) {
    const unsigned short* A = pass ? A2 : A1;
    const unsigned short* W = pass ? W2 : W1;
    const unsigned short* gA = A + (bm + srow) * KP + skoff;
    const unsigned short* gW = W + (bn + srow) * KP + skoff;
#pragma unroll 1
    for (int k0 = 0; k0 < KP; k0 += 32) {
      __syncthreads();
      gl_lds16(gA + k0, lA);
      gl_lds16(gA + k0 + 64 * KP, lA + 2048);
      gl_lds16(gW + k0, lB);
      gl_lds16(gW + k0 + 64 * KP, lB + 2048);
      __syncthreads();
      bf16x8 af[4], bg[4];
#pragma unroll
      for (int i = 0; i < 4; ++i)
        af[i] = *(const bf16x8*)&sA[(wm + 16 * i + l16) * 32 + quad * 8];
#pragma unroll
      for (int j = 0; j < 4; ++j)
        bg[j] = *(const bf16x8*)&sB[(wn + 16 * j + l16) * 32 + quad * 8];
#pragma unroll
      for (int i = 0; i < 4; ++i)
#pragma unroll
        for (int j = 0; j < 4; ++j)
          acc[i][j] = __builtin_amdgcn_mfma_f32_16x16x32_bf16(af[i], bg[j], acc[i][j], 0, 0, 0);
    }
  }

#pragma unroll
  for (int j = 0; j < 4; ++j) {
    const long long col = bn + wn + 16 * j + l16;
    const float bv = bias[col];
#pragma unroll
    for (int i = 0; i < 4; ++i) {
      const long long row0 = bm + wm + 16 * i + quad * 4;
#pragma unroll
      for (int r = 0; r < 4; ++r) {
        float v = acc[i][j][r] + bv;
        if (RELU) v = fmaxf(v, 0.f);
        C[(row0 + r) * (long long)N + col] = f2bf(v);
      }
    }
  }
}

// ---------------- graph boundaries ----------------
__global__ void bounds_k(const int* __restrict__ batch, int* __restrict__ gstart, int n, int G) {
  int g = blockIdx.x * blockDim.x + threadIdx.x;
  if (g > G) return;
  int lo = 0, hi = n;
  while (lo < hi) {
    int mid = (lo + hi) >> 1;
    if (batch[mid] < g) lo = mid + 1; else hi = mid;
  }
  gstart[g] = lo;
}

// ---------------- segment max pool ----------------
__global__ void segmax_k(const unsigned short* __restrict__ h2b, const int* __restrict__ gstart,
                         float* __restrict__ pooled) {
  int g = blockIdx.x;
  int c = blockIdx.y * 256 + threadIdx.x;
  int i0 = gstart[g], i1 = gstart[g + 1];
  float m = -3.4e38f;
  for (int i = i0; i < i1; ++i) m = fmaxf(m, bf2f(h2b[(size_t)i * D2 + c]));
  if (i0 >= i1) m = 0.f;
  pooled[(size_t)g * D2 + c] = m;
}

// ---------------- MLP head (fp32) ----------------
__global__ void head1_k(const float* __restrict__ pooled, const float* __restrict__ Wf1,
                        const float* __restrict__ bf1, float* __restrict__ hid) {
  int g = blockIdx.x, chunk = blockIdx.y;
  __shared__ float sp[2048];
  for (int i = threadIdx.x; i < 2048; i += 256) sp[i] = pooled[(size_t)g * 2048 + i];
  __syncthreads();
  int wave = threadIdx.x >> 6, lane = threadIdx.x & 63;
  for (int oi = wave; oi < 64; oi += 4) {
    int o = chunk * 64 + oi;
    const float4* wr = (const float4*)&Wf1[(size_t)o * 2048];
    float s = 0.f;
    for (int c = lane; c < 512; c += 64) {
      float4 wv = wr[c];
      float4 pv = *(const float4*)&sp[c * 4];
      s += wv.x * pv.x + wv.y * pv.y + wv.z * pv.z + wv.w * pv.w;
    }
    for (int off = 32; off; off >>= 1) s += __shfl_down(s, off);
    if (lane == 0) hid[(size_t)g * 1024 + o] = fmaxf(s + bf1[o], 0.f);
  }
}
__global__ void head2_k(const float* __restrict__ hid, const float* __restrict__ Wf2,
                        const float* __restrict__ bf2, float* __restrict__ out) {
  int g = blockIdx.x, t = threadIdx.x;
  __shared__ float sh[1024];
  __shared__ float red[256];
  for (int i = t; i < 1024; i += 256) sh[i] = hid[(size_t)g * 1024 + i];
  __syncthreads();
  for (int o = 0; o < 6; ++o) {
    float s = 0.f;
    for (int k = t; k < 1024; k += 256) s += sh[k] * Wf2[o * 1024 + k];
    red[t] = s;
    __syncthreads();
    for (int d = 128; d; d >>= 1) {
      if (t < d) red[t] += red[t + d];
      __syncthreads();
    }
    if (t == 0) out[g * 6 + o] = red[0] + bf2[o];
    __syncthreads();
  }
}

extern "C" void kernel_launch(void* const* d_in, const int* in_sizes, int n_in,
                              void* d_out, int out_size, void* d_ws, size_t ws_size,
                              hipStream_t stream) {
  const float* x    = (const float*)d_in[0];
  const int* ei     = (const int*)d_in[1];
  const int* batch  = (const int*)d_in[2];
  const float* W1l  = (const float*)d_in[3];
  const float* b1   = (const float*)d_in[4];
  const float* W1r  = (const float*)d_in[5];
  const float* W2l  = (const float*)d_in[6];
  const float* b2   = (const float*)d_in[7];
  const float* W2r  = (const float*)d_in[8];
  const float* Wf1  = (const float*)d_in[9];
  const float* bf1  = (const float*)d_in[10];
  const float* Wf2  = (const float*)d_in[11];
  const float* bf2  = (const float*)d_in[12];
  float* out = (float*)d_out;

  const int E = in_sizes[1] / 2;
  const int* srcp = ei;
  const int* dstp = ei + E;

  char* w = (char*)d_ws;
  auto take = [&](size_t b) {
    void* p = (void*)w;
    w += (b + 255) & ~(size_t)255;
    return p;
  };
  unsigned short* xb     = (unsigned short*)take((size_t)MP * K0 * 2);
  unsigned short* meanb  = (unsigned short*)take((size_t)MP * K0 * 2);
  unsigned short* h1b    = (unsigned short*)take((size_t)MP * D1 * 2);
  unsigned short* mean2b = (unsigned short*)take((size_t)MP * D1 * 2);
  unsigned short* h2b    = (unsigned short*)take((size_t)MP * D2 * 2);
  unsigned short* w1lb   = (unsigned short*)take((size_t)D1 * K0 * 2);
  unsigned short* w1rb   = (unsigned short*)take((size_t)D1 * K0 * 2);
  unsigned short* w2lb   = (unsigned short*)take((size_t)D2 * D1 * 2);
  unsigned short* w2rb   = (unsigned short*)take((size_t)D2 * D1 * 2);
  int* deg    = (int*)take((size_t)MP * 4);
  int* off    = (int*)take((size_t)(MP + 1) * 4);
  int* cursor = (int*)take((size_t)MP * 4);
  int* csr    = (int*)take((size_t)E * 4);
  int* gstart = (int*)take((size_t)(NG + 1) * 4);
  float* pooled = (float*)take((size_t)NG * D2 * 4);
  float* hid    = (float*)take((size_t)NG * 1024 * 4);

  cvt_pad<<<MP, 256, 0, stream>>>(x, xb, NN, D0, K0);
  cvt_pad<<<D1, 256, 0, stream>>>(W1l, w1lb, D1, D0, K0);
  cvt_pad<<<D1, 256, 0, stream>>>(W1r, w1rb, D1, D0, K0);
  cvt_pad<<<D2, 256, 0, stream>>>(W2l, w2lb, D2, D1, D1);
  cvt_pad<<<D2, 256, 0, stream>>>(W2r, w2rb, D2, D1, D1);

  zero_i<<<(MP + 255) / 256, 256, 0, stream>>>(deg, MP);
  count_k<<<(E + 255) / 256, 256, 0, stream>>>(dstp, deg, E, NN);
  scan_k<<<1, 1024, 0, stream>>>(deg, off, MP);
  copy_i<<<(MP + 255) / 256, 256, 0, stream>>>(off, cursor, MP);
  fill_k<<<(E + 255) / 256, 256, 0, stream>>>(srcp, dstp, cursor, csr, E, NN);

  agg_mean<<<MP, 256, 0, stream>>>(xb, off, csr, meanb, K0);
  gemm_dual<K0, D1, true><<<dim3(D1 / 128, MP / 128), 256, 0, stream>>>(
      meanb, w1lb, xb, w1rb, b1, h1b);

  agg_mean<<<MP, 256, 0, stream>>>(h1b, off, csr, mean2b, D1);
  gemm_dual<D1, D2, false><<<dim3(D2 / 128, MP / 128), 256, 0, stream>>>(
      mean2b, w2lb, h1b, w2rb, b2, h2b);

  bounds_k<<<1, 128, 0, stream>>>(batch, gstart, NN, NG);
  segmax_k<<<dim3(NG, D2 / 256), 256, 0, stream>>>(h2b, gstart, pooled);
  head1_k<<<dim3(NG, 16), 256, 0, stream>>>(pooled, Wf1, bf1, hid);
  head2_k<<<NG, 256, 0, stream>>>(hid, Wf2, bf2, out);
}

// Round 3
// 2260.890 us; speedup vs baseline: 1.1252x; 1.1251x over previous
//
#include <hip/hip_runtime.h>

typedef short bf16x8 __attribute__((ext_vector_type(8)));
typedef unsigned short u16x8 __attribute__((ext_vector_type(8)));
typedef char i8x16 __attribute__((ext_vector_type(16)));
typedef float f32x4 __attribute__((ext_vector_type(4)));

constexpr int NN = 50000;   // nodes
constexpr int NG = 64;      // graphs
constexpr int MP = 50048;   // nodes padded to 128 (391*128)
constexpr int D0 = 900;     // input feature dim
constexpr int K0 = 928;     // conv1 K padded to 32
constexpr int D1 = 1024;    // conv1 out dim / conv2 K
constexpr int D2 = 2048;    // conv2 out dim

__device__ __forceinline__ float bf2f(unsigned short u) {
  return __uint_as_float(((unsigned)u) << 16);
}
__device__ __forceinline__ unsigned short f2bf(float f) {
  unsigned x = __float_as_uint(f);
  return (unsigned short)((x + 0x7fffu + ((x >> 16) & 1u)) >> 16);
}

__device__ __forceinline__ void gl_lds16(const void* g, void* l) {
  __builtin_amdgcn_global_load_lds((const __attribute__((address_space(1))) void*)g,
                                   (__attribute__((address_space(3))) void*)l, 16, 0, 0);
}

// ------- x: fp32 -> bf16 (padded) + int8 with per-row scale -------
__global__ __launch_bounds__(256) void cvt_x(const float* __restrict__ in,
                                             unsigned short* __restrict__ xb,
                                             char* __restrict__ xi8,
                                             float* __restrict__ xscale) {
  int r = blockIdx.x;
  __shared__ float row[K0];
  __shared__ float smax[256];
  int t = threadIdx.x;
  float m = 0.f;
  for (int c = t; c < K0; c += 256) {
    float v = (r < NN && c < D0) ? in[(size_t)r * D0 + c] : 0.f;
    row[c] = v;
    m = fmaxf(m, fabsf(v));
  }
  smax[t] = m;
  __syncthreads();
  for (int dd = 128; dd; dd >>= 1) {
    if (t < dd) smax[t] = fmaxf(smax[t], smax[t + dd]);
    __syncthreads();
  }
  float mx = smax[0];
  float inv = mx > 0.f ? 127.f / mx : 0.f;
  for (int c = t; c < K0; c += 256) {
    float v = row[c];
    xb[(size_t)r * K0 + c] = f2bf(v);
    xi8[(size_t)r * K0 + c] = (char)(int)rintf(v * inv);
  }
  if (t == 0) xscale[r] = mx * (1.f / 127.f);
}

// ------- bf16 rows -> int8 with per-row scale (for h1) -------
__global__ __launch_bounds__(256) void quant_rows(const unsigned short* __restrict__ in,
                                                  char* __restrict__ q,
                                                  float* __restrict__ scale, int K) {
  int r = blockIdx.x;
  __shared__ float row[1024];
  __shared__ float smax[256];
  int t = threadIdx.x;
  float m = 0.f;
  for (int c = t; c < K; c += 256) {
    float v = bf2f(in[(size_t)r * K + c]);
    row[c] = v;
    m = fmaxf(m, fabsf(v));
  }
  smax[t] = m;
  __syncthreads();
  for (int dd = 128; dd; dd >>= 1) {
    if (t < dd) smax[t] = fmaxf(smax[t], smax[t + dd]);
    __syncthreads();
  }
  float mx = smax[0];
  float inv = mx > 0.f ? 127.f / mx : 0.f;
  for (int c = t; c < K; c += 256) q[(size_t)r * K + c] = (char)(int)rintf(row[c] * inv);
  if (t == 0) scale[r] = mx * (1.f / 127.f);
}

// ------- fp32 -> bf16 weight convert (padded) -------
__global__ void cvt_pad(const float* __restrict__ in, unsigned short* __restrict__ out,
                        int Rin, int Cin, int Cpad) {
  int r = blockIdx.x;
  const float* src = in + (size_t)r * Cin;
  unsigned short* dst = out + (size_t)r * Cpad;
  for (int c = threadIdx.x; c < Cpad; c += blockDim.x) {
    float v = (r < Rin && c < Cin) ? src[c] : 0.f;
    dst[c] = f2bf(v);
  }
}

// ---------------- CSR build ----------------
__global__ void zero_i(int* p, int n) {
  int i = blockIdx.x * blockDim.x + threadIdx.x;
  if (i < n) p[i] = 0;
}
__global__ void count_k(const int* __restrict__ dst, int* __restrict__ deg, int E, int n) {
  int e = blockIdx.x * blockDim.x + threadIdx.x;
  if (e < E) {
    int d = dst[e];
    if ((unsigned)d < (unsigned)n) atomicAdd(&deg[d], 1);
  }
}
__global__ void scan_k(const int* __restrict__ deg, int* __restrict__ off, int n) {
  __shared__ int s[1024];
  __shared__ int carry;
  int t = threadIdx.x;
  if (t == 0) carry = 0;
  __syncthreads();
  for (int base = 0; base < n; base += 1024) {
    int v = (base + t < n) ? deg[base + t] : 0;
    s[t] = v;
    __syncthreads();
    for (int d = 1; d < 1024; d <<= 1) {
      int x = (t >= d) ? s[t - d] : 0;
      __syncthreads();
      s[t] += x;
      __syncthreads();
    }
    if (base + t < n) off[base + t] = carry + s[t] - v;
    int total = s[1023];
    __syncthreads();
    if (t == 0) carry += total;
    __syncthreads();
  }
  if (t == 0) off[n] = carry;
}
__global__ void copy_i(const int* a, int* b, int n) {
  int i = blockIdx.x * blockDim.x + threadIdx.x;
  if (i < n) b[i] = a[i];
}
__global__ void fill_k(const int* __restrict__ src, const int* __restrict__ dst,
                       int* __restrict__ cursor, int* __restrict__ csr, int E, int n) {
  int e = blockIdx.x * blockDim.x + threadIdx.x;
  if (e < E) {
    int d = dst[e];
    if ((unsigned)d < (unsigned)n) {
      int p = atomicAdd(&cursor[d], 1);
      int s = src[e];
      if ((unsigned)s >= (unsigned)n) s = 0;
      csr[p] = s;
    }
  }
}

// ------- mean aggregation over int8 gather, per-src-row scale -------
// Block = 1 node, 4 waves split edges 4-way, 16 int8/lane (16B loads),
// 4-deep unroll, fp32 accumulate, LDS cross-wave reduce, bf16 out.
template <int K>
__global__ __launch_bounds__(256) void agg_mean_i8(const char* __restrict__ feat,
                                                   const float* __restrict__ scale,
                                                   const int* __restrict__ off,
                                                   const int* __restrict__ csr,
                                                   unsigned short* __restrict__ out) {
  __shared__ float red[3][1024];
  const int node = blockIdx.x;
  const int wave = threadIdx.x >> 6, lane = threadIdx.x & 63;
  const int d = lane * 16;
  const bool act = (d < K);
  const int e0 = off[node], e1 = off[node + 1];
  float a[16];
#pragma unroll
  for (int k = 0; k < 16; ++k) a[k] = 0.f;
  if (act) {
    const char* fp = feat + d;
    int e = e0 + wave;
    for (; e + 12 < e1; e += 16) {
      int s0 = csr[e], s1 = csr[e + 4], s2 = csr[e + 8], s3 = csr[e + 12];
      float c0 = scale[s0], c1 = scale[s1], c2 = scale[s2], c3 = scale[s3];
      i8x16 v0 = *(const i8x16*)(fp + (size_t)s0 * K);
      i8x16 v1 = *(const i8x16*)(fp + (size_t)s1 * K);
      i8x16 v2 = *(const i8x16*)(fp + (size_t)s2 * K);
      i8x16 v3 = *(const i8x16*)(fp + (size_t)s3 * K);
#pragma unroll
      for (int k = 0; k < 16; ++k) {
        a[k] += c0 * (float)v0[k];
        a[k] += c1 * (float)v1[k];
        a[k] += c2 * (float)v2[k];
        a[k] += c3 * (float)v3[k];
      }
    }
    for (; e < e1; e += 4) {
      int s = csr[e];
      float c = scale[s];
      i8x16 v = *(const i8x16*)(fp + (size_t)s * K);
#pragma unroll
      for (int k = 0; k < 16; ++k) a[k] += c * (float)v[k];
    }
  }
  if (wave > 0 && act) {
#pragma unroll
    for (int k = 0; k < 16; ++k) red[wave - 1][d + k] = a[k];
  }
  __syncthreads();
  if (wave == 0 && act) {
    int deg = e1 - e0;
    float inv = 1.f / (float)(deg > 1 ? deg : 1);
    u16x8 o0, o1;
#pragma unroll
    for (int k = 0; k < 8; ++k)
      o0[k] = f2bf((a[k] + red[0][d + k] + red[1][d + k] + red[2][d + k]) * inv);
#pragma unroll
    for (int k = 8; k < 16; ++k)
      o1[k - 8] = f2bf((a[k] + red[0][d + k] + red[1][d + k] + red[2][d + k]) * inv);
    *(u16x8*)&out[(size_t)node * K + d] = o0;
    *(u16x8*)&out[(size_t)node * K + d + 8] = o1;
  }
}

// ---------------- dual-operand bf16 MFMA GEMM, XOR-swizzled LDS ----------------
// LDS slot(row r, chunk c) = c ^ (r&3) ^ ((r>>2)&3); staging permutes each
// lane's GLOBAL chunk so the wave-uniform lane*16B LDS layout is the swizzled
// one; ds_read_b128 is then perfectly bank-balanced (2 lanes/bank-group).
template <int KP, int N, bool RELU>
__global__ __launch_bounds__(256) void gemm_dual(const unsigned short* __restrict__ A1,
                                                 const unsigned short* __restrict__ W1,
                                                 const unsigned short* __restrict__ A2,
                                                 const unsigned short* __restrict__ W2,
                                                 const float* __restrict__ bias,
                                                 unsigned short* __restrict__ C) {
  __shared__ unsigned short sA[128 * 32];
  __shared__ unsigned short sB[128 * 32];
  const int tid = threadIdx.x;
  const int wave = tid >> 6, lane = tid & 63;
  const int quad = lane >> 4, l16 = lane & 15;
  const int wm = (wave >> 1) * 64, wn = (wave & 1) * 64;
  const long long bm = (long long)blockIdx.y * 128;
  const long long bn = (long long)blockIdx.x * 128;

  const int srow = wave * 16 + (lane >> 2);
  const int skoff = (((lane & 3) ^ ((lane >> 2) & 3) ^ ((lane >> 4) & 3))) * 8;
  const int fsw = (l16 & 3) ^ ((l16 >> 2) & 3);      // fragment-read slot swizzle
  const int fslot = (quad ^ fsw) * 8;
  unsigned short* lA = &sA[wave * 512 + lane * 8];
  unsigned short* lB = &sB[wave * 512 + lane * 8];

  f32x4 acc[4][4];
#pragma unroll
  for (int i = 0; i < 4; ++i)
#pragma unroll
    for (int j = 0; j < 4; ++j) acc[i][j] = (f32x4){0.f, 0.f, 0.f, 0.f};

#pragma unroll 1
  for (int pass = 0; pass < 2; ++pass) {
    const unsigned short* A = pass ? A2 : A1;
    const unsigned short* W = pass ? W2 : W1;
    const unsigned short* gA = A + (bm + srow) * KP + skoff;
    const unsigned short* gW = W + (bn + srow) * KP + skoff;
#pragma unroll 1
    for (int k0 = 0; k0 < KP; k0 += 32) {
      __syncthreads();
      gl_lds16(gA + k0, lA);
      gl_lds16(gA + k0 + 64 * KP, lA + 2048);
      gl_lds16(gW + k0, lB);
      gl_lds16(gW + k0 + 64 * KP, lB + 2048);
      __syncthreads();
      bf16x8 af[4], bg[4];
#pragma unroll
      for (int i = 0; i < 4; ++i)
        af[i] = *(const bf16x8*)&sA[(wm + 16 * i + l16) * 32 + fslot];
#pragma unroll
      for (int j = 0; j < 4; ++j)
        bg[j] = *(const bf16x8*)&sB[(wn + 16 * j + l16) * 32 + fslot];
#pragma unroll
      for (int i = 0; i < 4; ++i)
#pragma unroll
        for (int j = 0; j < 4; ++j)
          acc[i][j] = __builtin_amdgcn_mfma_f32_16x16x32_bf16(af[i], bg[j], acc[i][j], 0, 0, 0);
    }
  }

#pragma unroll
  for (int j = 0; j < 4; ++j) {
    const long long col = bn + wn + 16 * j + l16;
    const float bv = bias[col];
#pragma unroll
    for (int i = 0; i < 4; ++i) {
      const long long row0 = bm + wm + 16 * i + quad * 4;
#pragma unroll
      for (int r = 0; r < 4; ++r) {
        float v = acc[i][j][r] + bv;
        if (RELU) v = fmaxf(v, 0.f);
        C[(row0 + r) * (long long)N + col] = f2bf(v);
      }
    }
  }
}

// ---------------- graph boundaries ----------------
__global__ void bounds_k(const int* __restrict__ batch, int* __restrict__ gstart, int n, int G) {
  int g = blockIdx.x * blockDim.x + threadIdx.x;
  if (g > G) return;
  int lo = 0, hi = n;
  while (lo < hi) {
    int mid = (lo + hi) >> 1;
    if (batch[mid] < g) lo = mid + 1; else hi = mid;
  }
  gstart[g] = lo;
}

// ---------------- segment max pool ----------------
__global__ void segmax_k(const unsigned short* __restrict__ h2b, const int* __restrict__ gstart,
                         float* __restrict__ pooled) {
  int g = blockIdx.x;
  int c = blockIdx.y * 256 + threadIdx.x;
  int i0 = gstart[g], i1 = gstart[g + 1];
  float m = -3.4e38f;
  for (int i = i0; i < i1; ++i) m = fmaxf(m, bf2f(h2b[(size_t)i * D2 + c]));
  if (i0 >= i1) m = 0.f;
  pooled[(size_t)g * D2 + c] = m;
}

// ---------------- MLP head (fp32) ----------------
__global__ void head1_k(const float* __restrict__ pooled, const float* __restrict__ Wf1,
                        const float* __restrict__ bf1, float* __restrict__ hid) {
  int g = blockIdx.x, chunk = blockIdx.y;
  __shared__ float sp[2048];
  for (int i = threadIdx.x; i < 2048; i += 256) sp[i] = pooled[(size_t)g * 2048 + i];
  __syncthreads();
  int wave = threadIdx.x >> 6, lane = threadIdx.x & 63;
  for (int oi = wave; oi < 64; oi += 4) {
    int o = chunk * 64 + oi;
    const float4* wr = (const float4*)&Wf1[(size_t)o * 2048];
    float s = 0.f;
    for (int c = lane; c < 512; c += 64) {
      float4 wv = wr[c];
      float4 pv = *(const float4*)&sp[c * 4];
      s += wv.x * pv.x + wv.y * pv.y + wv.z * pv.z + wv.w * pv.w;
    }
    for (int off = 32; off; off >>= 1) s += __shfl_down(s, off);
    if (lane == 0) hid[(size_t)g * 1024 + o] = fmaxf(s + bf1[o], 0.f);
  }
}
__global__ void head2_k(const float* __restrict__ hid, const float* __restrict__ Wf2,
                        const float* __restrict__ bf2, float* __restrict__ out) {
  int g = blockIdx.x, t = threadIdx.x;
  __shared__ float sh[1024];
  __shared__ float red[256];
  for (int i = t; i < 1024; i += 256) sh[i] = hid[(size_t)g * 1024 + i];
  __syncthreads();
  for (int o = 0; o < 6; ++o) {
    float s = 0.f;
    for (int k = t; k < 1024; k += 256) s += sh[k] * Wf2[o * 1024 + k];
    red[t] = s;
    __syncthreads();
    for (int d = 128; d; d >>= 1) {
      if (t < d) red[t] += red[t + d];
      __syncthreads();
    }
    if (t == 0) out[g * 6 + o] = red[0] + bf2[o];
    __syncthreads();
  }
}

extern "C" void kernel_launch(void* const* d_in, const int* in_sizes, int n_in,
                              void* d_out, int out_size, void* d_ws, size_t ws_size,
                              hipStream_t stream) {
  const float* x    = (const float*)d_in[0];
  const int* ei     = (const int*)d_in[1];
  const int* batch  = (const int*)d_in[2];
  const float* W1l  = (const float*)d_in[3];
  const float* b1   = (const float*)d_in[4];
  const float* W1r  = (const float*)d_in[5];
  const float* W2l  = (const float*)d_in[6];
  const float* b2   = (const float*)d_in[7];
  const float* W2r  = (const float*)d_in[8];
  const float* Wf1  = (const float*)d_in[9];
  const float* bf1  = (const float*)d_in[10];
  const float* Wf2  = (const float*)d_in[11];
  const float* bf2  = (const float*)d_in[12];
  float* out = (float*)d_out;

  const int E = in_sizes[1] / 2;
  const int* srcp = ei;
  const int* dstp = ei + E;

  char* w = (char*)d_ws;
  auto take = [&](size_t b) {
    void* p = (void*)w;
    w += (b + 255) & ~(size_t)255;
    return p;
  };
  unsigned short* xb     = (unsigned short*)take((size_t)MP * K0 * 2);  // dead after gemm1
  unsigned short* meanb  = (unsigned short*)take((size_t)MP * K0 * 2);  // dead after gemm1
  unsigned short* h1b    = (unsigned short*)take((size_t)MP * D1 * 2);
  unsigned short* h2b    = (unsigned short*)take((size_t)MP * D2 * 2);
  char* i8buf            = (char*)take((size_t)MP * D1);   // xi8 then h1i8
  float* scalebuf        = (float*)take((size_t)MP * 4);   // xscale then h1scale
  unsigned short* w1lb   = (unsigned short*)take((size_t)D1 * K0 * 2);
  unsigned short* w1rb   = (unsigned short*)take((size_t)D1 * K0 * 2);
  unsigned short* w2lb   = (unsigned short*)take((size_t)D2 * D1 * 2);
  unsigned short* w2rb   = (unsigned short*)take((size_t)D2 * D1 * 2);
  int* deg    = (int*)take((size_t)MP * 4);
  int* off    = (int*)take((size_t)(MP + 1) * 4);
  int* cursor = (int*)take((size_t)MP * 4);
  int* csr    = (int*)take((size_t)E * 4);
  int* gstart = (int*)take((size_t)(NG + 1) * 4);
  float* pooled = (float*)take((size_t)NG * D2 * 4);
  float* hid    = (float*)take((size_t)NG * 1024 * 4);
  // mean2b overlays the dead xb(+start of meanb) region: MP*D1*2 <= 2*MP*K0*2
  unsigned short* mean2b = (unsigned short*)xb;

  cvt_x<<<MP, 256, 0, stream>>>(x, xb, i8buf, scalebuf);
  cvt_pad<<<D1, 256, 0, stream>>>(W1l, w1lb, D1, D0, K0);
  cvt_pad<<<D1, 256, 0, stream>>>(W1r, w1rb, D1, D0, K0);
  cvt_pad<<<D2, 256, 0, stream>>>(W2l, w2lb, D2, D1, D1);
  cvt_pad<<<D2, 256, 0, stream>>>(W2r, w2rb, D2, D1, D1);

  zero_i<<<(MP + 255) / 256, 256, 0, stream>>>(deg, MP);
  count_k<<<(E + 255) / 256, 256, 0, stream>>>(dstp, deg, E, NN);
  scan_k<<<1, 1024, 0, stream>>>(deg, off, MP);
  copy_i<<<(MP + 255) / 256, 256, 0, stream>>>(off, cursor, MP);
  fill_k<<<(E + 255) / 256, 256, 0, stream>>>(srcp, dstp, cursor, csr, E, NN);

  // conv1: mean = agg(x_i8); h1 = relu(mean@W1l^T + x@W1r^T + b1)
  agg_mean_i8<K0><<<MP, 256, 0, stream>>>(i8buf, scalebuf, off, csr, meanb);
  gemm_dual<K0, D1, true><<<dim3(D1 / 128, MP / 128), 256, 0, stream>>>(
      meanb, w1lb, xb, w1rb, b1, h1b);

  // conv2: quantize h1, mean2 = agg(h1_i8); h2 = mean2@W2l^T + h1@W2r^T + b2
  quant_rows<<<MP, 256, 0, stream>>>(h1b, i8buf, scalebuf, D1);
  agg_mean_i8<D1><<<MP, 256, 0, stream>>>(i8buf, scalebuf, off, csr, mean2b);
  gemm_dual<D1, D2, false><<<dim3(D2 / 128, MP / 128), 256, 0, stream>>>(
      mean2b, w2lb, h1b, w2rb, b2, h2b);

  bounds_k<<<1, 128, 0, stream>>>(batch, gstart, NN, NG);
  segmax_k<<<dim3(NG, D2 / 256), 256, 0, stream>>>(h2b, gstart, pooled);
  head1_k<<<dim3(NG, 16), 256, 0, stream>>>(pooled, Wf1, bf1, hid);
  head2_k<<<NG, 256, 0, stream>>>(hid, Wf2, bf2, out);
}

// Round 4
// 2001.759 us; speedup vs baseline: 1.2708x; 1.1295x over previous
//
#include <hip/hip_runtime.h>

typedef unsigned short u16x8 __attribute__((ext_vector_type(8)));
typedef char i8x16 __attribute__((ext_vector_type(16)));
typedef int i32x4 __attribute__((ext_vector_type(4)));

constexpr int NN = 50000;   // nodes
constexpr int NG = 64;      // graphs
constexpr int MP = 50048;   // nodes padded to 128 (391*128)
constexpr int D0 = 900;     // input feature dim
constexpr int K0 = 960;     // conv1 K padded to 64 (int8 MFMA K-tile)
constexpr int D1 = 1024;    // conv1 out dim / conv2 K
constexpr int D2 = 2048;    // conv2 out dim

__device__ __forceinline__ float bf2f(unsigned short u) {
  return __uint_as_float(((unsigned)u) << 16);
}
__device__ __forceinline__ unsigned short f2bf(float f) {
  unsigned x = __float_as_uint(f);
  return (unsigned short)((x + 0x7fffu + ((x >> 16) & 1u)) >> 16);
}

__device__ __forceinline__ void gl_lds16(const void* g, void* l) {
  __builtin_amdgcn_global_load_lds((const __attribute__((address_space(1))) void*)g,
                                   (__attribute__((address_space(3))) void*)l, 16, 0, 0);
}

// ------- x: fp32 -> int8 with per-row scale (padded to K0) -------
__global__ __launch_bounds__(256) void cvt_x(const float* __restrict__ in,
                                             char* __restrict__ xi8,
                                             float* __restrict__ xscale) {
  int r = blockIdx.x;
  __shared__ float row[K0];
  __shared__ float smax[256];
  int t = threadIdx.x;
  float m = 0.f;
  for (int c = t; c < K0; c += 256) {
    float v = (r < NN && c < D0) ? in[(size_t)r * D0 + c] : 0.f;
    row[c] = v;
    m = fmaxf(m, fabsf(v));
  }
  smax[t] = m;
  __syncthreads();
  for (int dd = 128; dd; dd >>= 1) {
    if (t < dd) smax[t] = fmaxf(smax[t], smax[t + dd]);
    __syncthreads();
  }
  float mx = smax[0];
  float inv = mx > 0.f ? 127.f / mx : 0.f;
  for (int c = t; c < K0; c += 256) xi8[(size_t)r * K0 + c] = (char)(int)rintf(row[c] * inv);
  if (t == 0) xscale[r] = mx * (1.f / 127.f);
}

// ------- weight fp32 -> int8, per-out-row scale, K padded -------
__global__ __launch_bounds__(256) void wq_k(const float* __restrict__ in, int Cin, int KP,
                                            char* __restrict__ q, float* __restrict__ sc) {
  int r = blockIdx.x;
  __shared__ float smax[256];
  int t = threadIdx.x;
  float m = 0.f;
  for (int c = t; c < Cin; c += 256) m = fmaxf(m, fabsf(in[(size_t)r * Cin + c]));
  smax[t] = m;
  __syncthreads();
  for (int dd = 128; dd; dd >>= 1) {
    if (t < dd) smax[t] = fmaxf(smax[t], smax[t + dd]);
    __syncthreads();
  }
  float mx = smax[0];
  float inv = mx > 0.f ? 127.f / mx : 0.f;
  for (int c = t; c < KP; c += 256) {
    float v = (c < Cin) ? in[(size_t)r * Cin + c] : 0.f;
    q[(size_t)r * KP + c] = (char)(int)rintf(v * inv);
  }
  if (t == 0) sc[r] = mx * (1.f / 127.f);
}

// ------- bf16 rows -> int8 with per-row scale (h1) -------
__global__ __launch_bounds__(256) void quant_rows(const unsigned short* __restrict__ in,
                                                  char* __restrict__ q,
                                                  float* __restrict__ scale, int K) {
  int r = blockIdx.x;
  __shared__ float row[1024];
  __shared__ float smax[256];
  int t = threadIdx.x;
  float m = 0.f;
  for (int c = t; c < K; c += 256) {
    float v = bf2f(in[(size_t)r * K + c]);
    row[c] = v;
    m = fmaxf(m, fabsf(v));
  }
  smax[t] = m;
  __syncthreads();
  for (int dd = 128; dd; dd >>= 1) {
    if (t < dd) smax[t] = fmaxf(smax[t], smax[t + dd]);
    __syncthreads();
  }
  float mx = smax[0];
  float inv = mx > 0.f ? 127.f / mx : 0.f;
  for (int c = t; c < K; c += 256) q[(size_t)r * K + c] = (char)(int)rintf(row[c] * inv);
  if (t == 0) scale[r] = mx * (1.f / 127.f);
}

// ---------------- CSR build ----------------
__global__ void zero_i(int* p, int n) {
  int i = blockIdx.x * blockDim.x + threadIdx.x;
  if (i < n) p[i] = 0;
}
__global__ void count_k(const int* __restrict__ dst, int* __restrict__ deg, int E, int n) {
  int e = blockIdx.x * blockDim.x + threadIdx.x;
  if (e < E) {
    int d = dst[e];
    if ((unsigned)d < (unsigned)n) atomicAdd(&deg[d], 1);
  }
}
__global__ void scan_k(const int* __restrict__ deg, int* __restrict__ off, int n) {
  __shared__ int s[1024];
  __shared__ int carry;
  int t = threadIdx.x;
  if (t == 0) carry = 0;
  __syncthreads();
  for (int base = 0; base < n; base += 1024) {
    int v = (base + t < n) ? deg[base + t] : 0;
    s[t] = v;
    __syncthreads();
    for (int d = 1; d < 1024; d <<= 1) {
      int x = (t >= d) ? s[t - d] : 0;
      __syncthreads();
      s[t] += x;
      __syncthreads();
    }
    if (base + t < n) off[base + t] = carry + s[t] - v;
    int total = s[1023];
    __syncthreads();
    if (t == 0) carry += total;
    __syncthreads();
  }
  if (t == 0) off[n] = carry;
}
__global__ void copy_i(const int* a, int* b, int n) {
  int i = blockIdx.x * blockDim.x + threadIdx.x;
  if (i < n) b[i] = a[i];
}
__global__ void fill_k(const int* __restrict__ src, const int* __restrict__ dst,
                       int* __restrict__ cursor, int* __restrict__ csr, int E, int n) {
  int e = blockIdx.x * blockDim.x + threadIdx.x;
  if (e < E) {
    int d = dst[e];
    if ((unsigned)d < (unsigned)n) {
      int p = atomicAdd(&cursor[d], 1);
      int s = src[e];
      if ((unsigned)s >= (unsigned)n) s = 0;
      csr[p] = s;
    }
  }
}

// ------- mean aggregation over int8 gather -> int8 mean + row scale -------
// Block = 1 node, 4 waves split edges 4-way, 16 int8/lane (16B loads),
// fp32 accumulate, LDS cross-wave reduce, row-max shuffle reduce, int8 out.
template <int K>
__global__ __launch_bounds__(256) void agg_mean_i8q(const char* __restrict__ feat,
                                                    const float* __restrict__ scale,
                                                    const int* __restrict__ off,
                                                    const int* __restrict__ csr,
                                                    char* __restrict__ mean_i8,
                                                    float* __restrict__ smean) {
  __shared__ float red[3][1024];
  const int node = blockIdx.x;
  const int wave = threadIdx.x >> 6, lane = threadIdx.x & 63;
  const int d = lane * 16;
  const bool act = (d < K);
  const int e0 = off[node], e1 = off[node + 1];
  float a[16];
#pragma unroll
  for (int k = 0; k < 16; ++k) a[k] = 0.f;
  if (act) {
    const char* fp = feat + d;
    int e = e0 + wave;
    for (; e + 12 < e1; e += 16) {
      int s0 = csr[e], s1 = csr[e + 4], s2 = csr[e + 8], s3 = csr[e + 12];
      float c0 = scale[s0], c1 = scale[s1], c2 = scale[s2], c3 = scale[s3];
      i8x16 v0 = *(const i8x16*)(fp + (size_t)s0 * K);
      i8x16 v1 = *(const i8x16*)(fp + (size_t)s1 * K);
      i8x16 v2 = *(const i8x16*)(fp + (size_t)s2 * K);
      i8x16 v3 = *(const i8x16*)(fp + (size_t)s3 * K);
#pragma unroll
      for (int k = 0; k < 16; ++k) {
        a[k] += c0 * (float)v0[k];
        a[k] += c1 * (float)v1[k];
        a[k] += c2 * (float)v2[k];
        a[k] += c3 * (float)v3[k];
      }
    }
    for (; e < e1; e += 4) {
      int s = csr[e];
      float c = scale[s];
      i8x16 v = *(const i8x16*)(fp + (size_t)s * K);
#pragma unroll
      for (int k = 0; k < 16; ++k) a[k] += c * (float)v[k];
    }
  }
  if (wave > 0 && act) {
#pragma unroll
    for (int k = 0; k < 16; ++k) red[wave - 1][d + k] = a[k];
  }
  __syncthreads();
  if (wave == 0) {
    int deg = e1 - e0;
    float inv = 1.f / (float)(deg > 1 ? deg : 1);
    float m[16];
    float mx = 0.f;
    if (act) {
#pragma unroll
      for (int k = 0; k < 16; ++k) {
        m[k] = (a[k] + red[0][d + k] + red[1][d + k] + red[2][d + k]) * inv;
        mx = fmaxf(mx, fabsf(m[k]));
      }
    }
    // max across the 64 lanes of wave 0
    for (int o = 32; o; o >>= 1) mx = fmaxf(mx, __shfl_down(mx, o));
    mx = __shfl(mx, 0);
    if (lane == 0) smean[node] = mx * (1.f / 127.f);
    float qi = mx > 0.f ? 127.f / mx : 0.f;
    if (act) {
      i8x16 q;
#pragma unroll
      for (int k = 0; k < 16; ++k) q[k] = (char)(int)rintf(m[k] * qi);
      *(i8x16*)&mean_i8[(size_t)node * K + d] = q;
    }
  }
}

// ---------------- dual-operand int8 MFMA GEMM ----------------
// C = relu?( (A1 i8 · W1 i8)·sA1(r)·sW1(c) + (A2·W2)·sA2(r)·sW2(c) + bias ), bf16 out.
// 128x128 tile, 4 waves 64x64, mfma_i32_16x16x64_i8, pass-1 partial held as
// packed bf16 (32 VGPRs) so one i32 accumulator serves both passes.
__device__ __forceinline__ void kloop_i8(const char* __restrict__ gA,
                                         const char* __restrict__ gW,
                                         char* lA, char* lB, char* sA, char* sB, int KP,
                                         i32x4 (&iacc)[4][4], int wm, int wn, int l16,
                                         int quad) {
#pragma unroll 1
  for (int k0 = 0; k0 < KP; k0 += 64) {
    __syncthreads();  // previous iteration's LDS reads complete
    gl_lds16(gA + k0, lA);
    gl_lds16(gA + k0 + (size_t)64 * KP, lA + 4096);
    gl_lds16(gW + k0, lB);
    gl_lds16(gW + k0 + (size_t)64 * KP, lB + 4096);
    __syncthreads();  // staging complete
    i32x4 af[4], bg[4];
#pragma unroll
    for (int i = 0; i < 4; ++i)
      af[i] = *(const i32x4*)&sA[(wm + 16 * i + l16) * 64 + quad * 16];
#pragma unroll
    for (int j = 0; j < 4; ++j)
      bg[j] = *(const i32x4*)&sB[(wn + 16 * j + l16) * 64 + quad * 16];
#pragma unroll
    for (int i = 0; i < 4; ++i)
#pragma unroll
      for (int j = 0; j < 4; ++j)
        iacc[i][j] = __builtin_amdgcn_mfma_i32_16x16x64_i8(af[i], bg[j], iacc[i][j], 0, 0, 0);
  }
}

template <int KP, int N, bool RELU>
__global__ __launch_bounds__(256) void gemm_i8_dual(
    const char* __restrict__ A1, const char* __restrict__ W1,
    const char* __restrict__ A2, const char* __restrict__ W2,
    const float* __restrict__ sA1, const float* __restrict__ sW1,
    const float* __restrict__ sA2, const float* __restrict__ sW2,
    const float* __restrict__ bias, unsigned short* __restrict__ C) {
  __shared__ char sA[128 * 64];
  __shared__ char sB[128 * 64];
  __shared__ float sc0[128], sc1[128], sc2[128], sc3[128];
  const int tid = threadIdx.x;
  const int wave = tid >> 6, lane = tid & 63;
  const int quad = lane >> 4, l16 = lane & 15;
  const int wm = (wave >> 1) * 64, wn = (wave & 1) * 64;
  const long long bm = (long long)blockIdx.y * 128;
  const long long bn = (long long)blockIdx.x * 128;

  if (tid < 128) {
    sc0[tid] = sA1[bm + tid];
    sc2[tid] = sA2[bm + tid];
  } else {
    sc1[tid - 128] = sW1[bn + tid - 128];
    sc3[tid - 128] = sW2[bn + tid - 128];
  }

  const int srow = wave * 16 + (lane >> 2);
  const int skoff = (lane & 3) * 16;
  char* lA = &sA[wave * 1024 + lane * 16];
  char* lB = &sB[wave * 1024 + lane * 16];

  i32x4 iacc[4][4];
#pragma unroll
  for (int i = 0; i < 4; ++i)
#pragma unroll
    for (int j = 0; j < 4; ++j) iacc[i][j] = (i32x4){0, 0, 0, 0};

  // pass 1: A1 · W1
  kloop_i8(A1 + (bm + srow) * (long long)KP + skoff, W1 + (bn + srow) * (long long)KP + skoff,
           lA, lB, sA, sB, KP, iacc, wm, wn, l16, quad);

  // dequant pass-1 into packed bf16 partials; reset iacc
  unsigned int fb[4][4][2];
#pragma unroll
  for (int i = 0; i < 4; ++i) {
    const int rowb = wm + 16 * i + quad * 4;
#pragma unroll
    for (int j = 0; j < 4; ++j) {
      const float cw = sc1[wn + 16 * j + l16];
      float v0 = (float)iacc[i][j][0] * sc0[rowb + 0] * cw;
      float v1 = (float)iacc[i][j][1] * sc0[rowb + 1] * cw;
      float v2 = (float)iacc[i][j][2] * sc0[rowb + 2] * cw;
      float v3 = (float)iacc[i][j][3] * sc0[rowb + 3] * cw;
      fb[i][j][0] = (unsigned)f2bf(v0) | ((unsigned)f2bf(v1) << 16);
      fb[i][j][1] = (unsigned)f2bf(v2) | ((unsigned)f2bf(v3) << 16);
      iacc[i][j] = (i32x4){0, 0, 0, 0};
    }
  }

  // pass 2: A2 · W2
  kloop_i8(A2 + (bm + srow) * (long long)KP + skoff, W2 + (bn + srow) * (long long)KP + skoff,
           lA, lB, sA, sB, KP, iacc, wm, wn, l16, quad);

#pragma unroll
  for (int j = 0; j < 4; ++j) {
    const int coll = wn + 16 * j + l16;
    const long long col = bn + coll;
    const float bv = bias[col];
    const float cw2 = sc3[coll];
#pragma unroll
    for (int i = 0; i < 4; ++i) {
      const int rowb = wm + 16 * i + quad * 4;
      const long long row0 = bm + rowb;
#pragma unroll
      for (int r = 0; r < 4; ++r) {
        float p1 = bf2f((unsigned short)(fb[i][j][r >> 1] >> ((r & 1) * 16)));
        float v = p1 + (float)iacc[i][j][r] * sc2[rowb + r] * cw2 + bv;
        if (RELU) v = fmaxf(v, 0.f);
        C[(row0 + r) * (long long)N + col] = f2bf(v);
      }
    }
  }
}

// ---------------- graph boundaries ----------------
__global__ void bounds_k(const int* __restrict__ batch, int* __restrict__ gstart, int n, int G) {
  int g = blockIdx.x * blockDim.x + threadIdx.x;
  if (g > G) return;
  int lo = 0, hi = n;
  while (lo < hi) {
    int mid = (lo + hi) >> 1;
    if (batch[mid] < g) lo = mid + 1; else hi = mid;
  }
  gstart[g] = lo;
}

// ---------------- segment max pool ----------------
__global__ void segmax_k(const unsigned short* __restrict__ h2b, const int* __restrict__ gstart,
                         float* __restrict__ pooled) {
  int g = blockIdx.x;
  int c = blockIdx.y * 256 + threadIdx.x;
  int i0 = gstart[g], i1 = gstart[g + 1];
  float m = -3.4e38f;
  for (int i = i0; i < i1; ++i) m = fmaxf(m, bf2f(h2b[(size_t)i * D2 + c]));
  if (i0 >= i1) m = 0.f;
  pooled[(size_t)g * D2 + c] = m;
}

// ---------------- MLP head (fp32) ----------------
__global__ void head1_k(const float* __restrict__ pooled, const float* __restrict__ Wf1,
                        const float* __restrict__ bf1, float* __restrict__ hid) {
  int g = blockIdx.x, chunk = blockIdx.y;
  __shared__ float sp[2048];
  for (int i = threadIdx.x; i < 2048; i += 256) sp[i] = pooled[(size_t)g * 2048 + i];
  __syncthreads();
  int wave = threadIdx.x >> 6, lane = threadIdx.x & 63;
  for (int oi = wave; oi < 64; oi += 4) {
    int o = chunk * 64 + oi;
    const float4* wr = (const float4*)&Wf1[(size_t)o * 2048];
    float s = 0.f;
    for (int c = lane; c < 512; c += 64) {
      float4 wv = wr[c];
      float4 pv = *(const float4*)&sp[c * 4];
      s += wv.x * pv.x + wv.y * pv.y + wv.z * pv.z + wv.w * pv.w;
    }
    for (int off = 32; off; off >>= 1) s += __shfl_down(s, off);
    if (lane == 0) hid[(size_t)g * 1024 + o] = fmaxf(s + bf1[o], 0.f);
  }
}
__global__ void head2_k(const float* __restrict__ hid, const float* __restrict__ Wf2,
                        const float* __restrict__ bf2, float* __restrict__ out) {
  int g = blockIdx.x, t = threadIdx.x;
  __shared__ float sh[1024];
  __shared__ float red[256];
  for (int i = t; i < 1024; i += 256) sh[i] = hid[(size_t)g * 1024 + i];
  __syncthreads();
  for (int o = 0; o < 6; ++o) {
    float s = 0.f;
    for (int k = t; k < 1024; k += 256) s += sh[k] * Wf2[o * 1024 + k];
    red[t] = s;
    __syncthreads();
    for (int d = 128; d; d >>= 1) {
      if (t < d) red[t] += red[t + d];
      __syncthreads();
    }
    if (t == 0) out[g * 6 + o] = red[0] + bf2[o];
    __syncthreads();
  }
}

extern "C" void kernel_launch(void* const* d_in, const int* in_sizes, int n_in,
                              void* d_out, int out_size, void* d_ws, size_t ws_size,
                              hipStream_t stream) {
  const float* x    = (const float*)d_in[0];
  const int* ei     = (const int*)d_in[1];
  const int* batch  = (const int*)d_in[2];
  const float* W1l  = (const float*)d_in[3];
  const float* b1   = (const float*)d_in[4];
  const float* W1r  = (const float*)d_in[5];
  const float* W2l  = (const float*)d_in[6];
  const float* b2   = (const float*)d_in[7];
  const float* W2r  = (const float*)d_in[8];
  const float* Wf1  = (const float*)d_in[9];
  const float* bf1  = (const float*)d_in[10];
  const float* Wf2  = (const float*)d_in[11];
  const float* bf2  = (const float*)d_in[12];
  float* out = (float*)d_out;

  const int E = in_sizes[1] / 2;
  const int* srcp = ei;
  const int* dstp = ei + E;

  char* w = (char*)d_ws;
  auto take = [&](size_t b) {
    void* p = (void*)w;
    w += (b + 255) & ~(size_t)255;
    return p;
  };
  char* xi8       = (char*)take((size_t)MP * K0);
  char* mean_i8   = (char*)take((size_t)MP * K0);
  char* h1_i8     = (char*)take((size_t)MP * D1);
  char* mean2_i8  = (char*)take((size_t)MP * D1);
  unsigned short* h1b = (unsigned short*)take((size_t)MP * D1 * 2);
  unsigned short* h2b = (unsigned short*)take((size_t)MP * D2 * 2);
  char* w1l_i8    = (char*)take((size_t)D1 * K0);
  char* w1r_i8    = (char*)take((size_t)D1 * K0);
  char* w2l_i8    = (char*)take((size_t)D2 * D1);
  char* w2r_i8    = (char*)take((size_t)D2 * D1);
  float* xscale   = (float*)take((size_t)MP * 4);
  float* smean    = (float*)take((size_t)MP * 4);
  float* h1scale  = (float*)take((size_t)MP * 4);
  float* smean2   = (float*)take((size_t)MP * 4);
  float* sW1l     = (float*)take((size_t)D1 * 4);
  float* sW1r     = (float*)take((size_t)D1 * 4);
  float* sW2l     = (float*)take((size_t)D2 * 4);
  float* sW2r     = (float*)take((size_t)D2 * 4);
  int* deg    = (int*)take((size_t)MP * 4);
  int* off    = (int*)take((size_t)(MP + 1) * 4);
  int* cursor = (int*)take((size_t)MP * 4);
  int* csr    = (int*)take((size_t)E * 4);
  int* gstart = (int*)take((size_t)(NG + 1) * 4);
  float* pooled = (float*)take((size_t)NG * D2 * 4);
  float* hid    = (float*)take((size_t)NG * 1024 * 4);

  cvt_x<<<MP, 256, 0, stream>>>(x, xi8, xscale);
  wq_k<<<D1, 256, 0, stream>>>(W1l, D0, K0, w1l_i8, sW1l);
  wq_k<<<D1, 256, 0, stream>>>(W1r, D0, K0, w1r_i8, sW1r);
  wq_k<<<D2, 256, 0, stream>>>(W2l, D1, D1, w2l_i8, sW2l);
  wq_k<<<D2, 256, 0, stream>>>(W2r, D1, D1, w2r_i8, sW2r);

  zero_i<<<(MP + 255) / 256, 256, 0, stream>>>(deg, MP);
  count_k<<<(E + 255) / 256, 256, 0, stream>>>(dstp, deg, E, NN);
  scan_k<<<1, 1024, 0, stream>>>(deg, off, MP);
  copy_i<<<(MP + 255) / 256, 256, 0, stream>>>(off, cursor, MP);
  fill_k<<<(E + 255) / 256, 256, 0, stream>>>(srcp, dstp, cursor, csr, E, NN);

  // conv1: mean = agg(x_i8) -> i8; h1 = relu(mean@W1l^T + x@W1r^T + b1)
  agg_mean_i8q<K0><<<MP, 256, 0, stream>>>(xi8, xscale, off, csr, mean_i8, smean);
  gemm_i8_dual<K0, D1, true><<<dim3(D1 / 128, MP / 128), 256, 0, stream>>>(
      mean_i8, w1l_i8, xi8, w1r_i8, smean, sW1l, xscale, sW1r, b1, h1b);

  // conv2: quantize h1; mean2 = agg(h1_i8) -> i8; h2 = mean2@W2l^T + h1@W2r^T + b2
  quant_rows<<<MP, 256, 0, stream>>>(h1b, h1_i8, h1scale, D1);
  agg_mean_i8q<D1><<<MP, 256, 0, stream>>>(h1_i8, h1scale, off, csr, mean2_i8, smean2);
  gemm_i8_dual<D1, D2, false><<<dim3(D2 / 128, MP / 128), 256, 0, stream>>>(
      mean2_i8, w2l_i8, h1_i8, w2r_i8, smean2, sW2l, h1scale, sW2r, b2, h2b);

  bounds_k<<<1, 128, 0, stream>>>(batch, gstart, NN, NG);
  segmax_k<<<dim3(NG, D2 / 256), 256, 0, stream>>>(h2b, gstart, pooled);
  head1_k<<<dim3(NG, 16), 256, 0, stream>>>(pooled, Wf1, bf1, hid);
  head2_k<<<NG, 256, 0, stream>>>(hid, Wf2, bf2, out);
}

// Round 5
// 1846.112 us; speedup vs baseline: 1.3780x; 1.0843x over previous
//
#include <hip/hip_runtime.h>

typedef unsigned short u16x8 __attribute__((ext_vector_type(8)));
typedef char i8x16 __attribute__((ext_vector_type(16)));
typedef int i32x4 __attribute__((ext_vector_type(4)));

constexpr int NN = 50000;   // nodes
constexpr int NG = 64;      // graphs
constexpr int MP = 50048;   // nodes padded to 128 (391*128)
constexpr int D0 = 900;     // input feature dim
constexpr int K0 = 960;     // conv1 half-K padded to 64
constexpr int D1 = 1024;    // conv1 out dim / conv2 half-K
constexpr int D2 = 2048;    // conv2 out dim
constexpr int KC1 = 2 * K0; // conv1 concatenated K = 1920
constexpr int KC2 = 2 * D1; // conv2 concatenated K = 2048

__device__ __forceinline__ float bf2f(unsigned short u) {
  return __uint_as_float(((unsigned)u) << 16);
}
__device__ __forceinline__ unsigned short f2bf(float f) {
  unsigned x = __float_as_uint(f);
  return (unsigned short)((x + 0x7fffu + ((x >> 16) & 1u)) >> 16);
}

__device__ __forceinline__ void gl_lds16(const void* g, void* l) {
  __builtin_amdgcn_global_load_lds((const __attribute__((address_space(1))) void*)g,
                                   (__attribute__((address_space(3))) void*)l, 16, 0, 0);
}

// ------- x: fp32 -> int8 into x-half of cat1, per-row scale -------
__global__ __launch_bounds__(256) void cvt_x(const float* __restrict__ in,
                                             char* __restrict__ cat1,
                                             float* __restrict__ xscale) {
  int r = blockIdx.x;
  __shared__ float row[K0];
  __shared__ float smax[256];
  int t = threadIdx.x;
  float m = 0.f;
  for (int c = t; c < K0; c += 256) {
    float v = (r < NN && c < D0) ? in[(size_t)r * D0 + c] : 0.f;
    row[c] = v;
    m = fmaxf(m, fabsf(v));
  }
  smax[t] = m;
  __syncthreads();
  for (int dd = 128; dd; dd >>= 1) {
    if (t < dd) smax[t] = fmaxf(smax[t], smax[t + dd]);
    __syncthreads();
  }
  float mx = smax[0];
  float inv = mx > 0.f ? 127.f / mx : 0.f;
  char* dst = cat1 + (size_t)r * KC1 + K0;  // x goes in second half
  for (int c = t; c < K0; c += 256) dst[c] = (char)(int)rintf(row[c] * inv);
  if (t == 0) xscale[r] = mx * (1.f / 127.f);
}

// ------- weights: [Wl | Wr] -> int8 cat with shared per-out-row scale -------
__global__ __launch_bounds__(256) void wq_cat(const float* __restrict__ Wl,
                                              const float* __restrict__ Wr, int Cin, int KH,
                                              char* __restrict__ q, float* __restrict__ sc) {
  int r = blockIdx.x, t = threadIdx.x;
  __shared__ float smax[256];
  float m = 0.f;
  for (int c = t; c < Cin; c += 256) {
    m = fmaxf(m, fabsf(Wl[(size_t)r * Cin + c]));
    m = fmaxf(m, fabsf(Wr[(size_t)r * Cin + c]));
  }
  smax[t] = m;
  __syncthreads();
  for (int dd = 128; dd; dd >>= 1) {
    if (t < dd) smax[t] = fmaxf(smax[t], smax[t + dd]);
    __syncthreads();
  }
  float mx = smax[0];
  float inv = mx > 0.f ? 127.f / mx : 0.f;
  char* row = q + (size_t)r * 2 * KH;
  for (int c = t; c < KH; c += 256) {
    row[c]      = (c < Cin) ? (char)(int)rintf(Wl[(size_t)r * Cin + c] * inv) : 0;
    row[KH + c] = (c < Cin) ? (char)(int)rintf(Wr[(size_t)r * Cin + c] * inv) : 0;
  }
  if (t == 0) sc[r] = mx * (1.f / 127.f);
}

// ------- h1 bf16 rows -> int8 into h1-half of cat2, per-row scale -------
__global__ __launch_bounds__(256) void quant_rows(const unsigned short* __restrict__ in,
                                                  char* __restrict__ cat2,
                                                  float* __restrict__ scale) {
  int r = blockIdx.x;
  __shared__ float row[D1];
  __shared__ float smax[256];
  int t = threadIdx.x;
  float m = 0.f;
  for (int c = t; c < D1; c += 256) {
    float v = bf2f(in[(size_t)r * D1 + c]);
    row[c] = v;
    m = fmaxf(m, fabsf(v));
  }
  smax[t] = m;
  __syncthreads();
  for (int dd = 128; dd; dd >>= 1) {
    if (t < dd) smax[t] = fmaxf(smax[t], smax[t + dd]);
    __syncthreads();
  }
  float mx = smax[0];
  float inv = mx > 0.f ? 127.f / mx : 0.f;
  char* dst = cat2 + (size_t)r * KC2 + D1;  // h1 goes in second half
  for (int c = t; c < D1; c += 256) dst[c] = (char)(int)rintf(row[c] * inv);
  if (t == 0) scale[r] = mx * (1.f / 127.f);
}

// ---------------- CSR build ----------------
__global__ void zero_i(int* p, int n) {
  int i = blockIdx.x * blockDim.x + threadIdx.x;
  if (i < n) p[i] = 0;
}
__global__ void count_k(const int* __restrict__ dst, int* __restrict__ deg, int E, int n) {
  int e = blockIdx.x * blockDim.x + threadIdx.x;
  if (e < E) {
    int d = dst[e];
    if ((unsigned)d < (unsigned)n) atomicAdd(&deg[d], 1);
  }
}
// hierarchical scan: block-local -> block sums -> add offsets
__global__ void scan1_k(const int* __restrict__ deg, int* __restrict__ off,
                        int* __restrict__ bsum, int n) {
  __shared__ int s[256];
  int t = threadIdx.x;
  int gid = blockIdx.x * 256 + t;
  int v = (gid < n) ? deg[gid] : 0;
  s[t] = v;
  __syncthreads();
  for (int d = 1; d < 256; d <<= 1) {
    int x = (t >= d) ? s[t - d] : 0;
    __syncthreads();
    s[t] += x;
    __syncthreads();
  }
  if (gid < n) off[gid] = s[t] - v;
  if (t == 255) bsum[blockIdx.x] = s[255];
}
__global__ void scan2_k(int* __restrict__ bsum, int nb) {
  __shared__ int s[256];
  int t = threadIdx.x;
  int v = (t < nb) ? bsum[t] : 0;
  s[t] = v;
  __syncthreads();
  for (int d = 1; d < 256; d <<= 1) {
    int x = (t >= d) ? s[t - d] : 0;
    __syncthreads();
    s[t] += x;
    __syncthreads();
  }
  if (t < nb) bsum[t] = s[t] - v;
  if (t == 255) bsum[nb] = s[255];
}
__global__ void scan3_k(int* __restrict__ off, const int* __restrict__ bsum, int n, int nb) {
  int gid = blockIdx.x * 256 + threadIdx.x;
  if (gid < n) off[gid] += bsum[gid >> 8];
  if (gid == 0) off[n] = bsum[nb];
}
__global__ void copy_i(const int* a, int* b, int n) {
  int i = blockIdx.x * blockDim.x + threadIdx.x;
  if (i < n) b[i] = a[i];
}
__global__ void fill_k(const int* __restrict__ src, const int* __restrict__ dst,
                       int* __restrict__ cursor, int* __restrict__ csr, int E, int n) {
  int e = blockIdx.x * blockDim.x + threadIdx.x;
  if (e < E) {
    int d = dst[e];
    if ((unsigned)d < (unsigned)n) {
      int p = atomicAdd(&cursor[d], 1);
      int s = src[e];
      if ((unsigned)s >= (unsigned)n) s = 0;
      csr[p] = s;
    }
  }
}

// ------- mean aggregation: one wave per node, int8 gather, int8 out -------
// Gathers the second-half (feature) columns of cat, writes quantized mean into
// the first-half columns, reusing the row's precomputed scale (clamped).
template <int K, int STRIDE>
__global__ __launch_bounds__(256) void agg_mean_i8w(char* __restrict__ cat,
                                                    const float* __restrict__ rscale,
                                                    const int* __restrict__ off,
                                                    const int* __restrict__ csr) {
  const int node = blockIdx.x * 4 + (threadIdx.x >> 6);
  const int lane = threadIdx.x & 63;
  const int d = lane * 16;
  const bool act = (d < K);
  const int e0 = off[node], e1 = off[node + 1];
  float a[16];
#pragma unroll
  for (int k = 0; k < 16; ++k) a[k] = 0.f;
  if (act) {
    const char* fp = cat + (size_t)K + d;  // feature half base + lane offset
    int e = e0;
    for (; e + 7 < e1; e += 8) {
      int s0 = csr[e],     s1 = csr[e + 1], s2 = csr[e + 2], s3 = csr[e + 3];
      int s4 = csr[e + 4], s5 = csr[e + 5], s6 = csr[e + 6], s7 = csr[e + 7];
      i8x16 v0 = *(const i8x16*)(fp + (size_t)s0 * STRIDE);
      i8x16 v1 = *(const i8x16*)(fp + (size_t)s1 * STRIDE);
      i8x16 v2 = *(const i8x16*)(fp + (size_t)s2 * STRIDE);
      i8x16 v3 = *(const i8x16*)(fp + (size_t)s3 * STRIDE);
      i8x16 v4 = *(const i8x16*)(fp + (size_t)s4 * STRIDE);
      i8x16 v5 = *(const i8x16*)(fp + (size_t)s5 * STRIDE);
      i8x16 v6 = *(const i8x16*)(fp + (size_t)s6 * STRIDE);
      i8x16 v7 = *(const i8x16*)(fp + (size_t)s7 * STRIDE);
      float c0 = rscale[s0], c1 = rscale[s1], c2 = rscale[s2], c3 = rscale[s3];
      float c4 = rscale[s4], c5 = rscale[s5], c6 = rscale[s6], c7 = rscale[s7];
#pragma unroll
      for (int k = 0; k < 16; ++k) {
        a[k] += c0 * (float)v0[k] + c1 * (float)v1[k] + c2 * (float)v2[k] + c3 * (float)v3[k];
        a[k] += c4 * (float)v4[k] + c5 * (float)v5[k] + c6 * (float)v6[k] + c7 * (float)v7[k];
      }
    }
    for (; e < e1; ++e) {
      int s = csr[e];
      float c = rscale[s];
      i8x16 v = *(const i8x16*)(fp + (size_t)s * STRIDE);
#pragma unroll
      for (int k = 0; k < 16; ++k) a[k] += c * (float)v[k];
    }
  }
  if (act) {
    int deg = e1 - e0;
    float inv = 1.f / (float)(deg > 1 ? deg : 1);
    float sc = rscale[node];
    float qi = sc > 0.f ? 1.f / sc : 0.f;  // quantize mean with row's own scale
    i8x16 q;
#pragma unroll
    for (int k = 0; k < 16; ++k) {
      float m = a[k] * inv * qi;
      m = fminf(fmaxf(rintf(m), -127.f), 127.f);
      q[k] = (char)(int)m;
    }
    *(i8x16*)&cat[(size_t)node * STRIDE + d] = q;  // mean half
  }
}

// ---------------- single-pass K-concatenated int8 MFMA GEMM ----------------
// C[m,n] = relu?( sA(m)*sW(n)*sum_k A[m,k]W[n,k] + bias[n] ), bf16 out.
// 128x128 tile, 4 waves 64x64, mfma_i32_16x16x64_i8, global_load_lds staging.
template <int KP, int N, bool RELU>
__global__ __launch_bounds__(256, 5) void gemm_i8(const char* __restrict__ A,
                                                  const char* __restrict__ W,
                                                  const float* __restrict__ sA_,
                                                  const float* __restrict__ sW_,
                                                  const float* __restrict__ bias,
                                                  unsigned short* __restrict__ C) {
  __shared__ char sA[128 * 64];
  __shared__ char sB[128 * 64];
  __shared__ float sc0[128], sc1[128];
  const int tid = threadIdx.x;
  const int wave = tid >> 6, lane = tid & 63;
  const int quad = lane >> 4, l16 = lane & 15;
  const int wm = (wave >> 1) * 64, wn = (wave & 1) * 64;
  const long long bm = (long long)blockIdx.y * 128;
  const long long bn = (long long)blockIdx.x * 128;

  if (tid < 128) sc0[tid] = sA_[bm + tid];
  else sc1[tid - 128] = sW_[bn + tid - 128];

  const int srow = wave * 16 + (lane >> 2);
  const int skoff = (lane & 3) * 16;
  char* lA = &sA[wave * 1024 + lane * 16];
  char* lB = &sB[wave * 1024 + lane * 16];
  const char* gA = A + (bm + srow) * (long long)KP + skoff;
  const char* gW = W + (bn + srow) * (long long)KP + skoff;

  i32x4 iacc[4][4];
#pragma unroll
  for (int i = 0; i < 4; ++i)
#pragma unroll
    for (int j = 0; j < 4; ++j) iacc[i][j] = (i32x4){0, 0, 0, 0};

#pragma unroll 1
  for (int k0 = 0; k0 < KP; k0 += 64) {
    __syncthreads();  // previous iteration's LDS reads complete
    gl_lds16(gA + k0, lA);
    gl_lds16(gA + k0 + (size_t)64 * KP, lA + 4096);
    gl_lds16(gW + k0, lB);
    gl_lds16(gW + k0 + (size_t)64 * KP, lB + 4096);
    __syncthreads();  // staging complete
    i32x4 af[4], bg[4];
#pragma unroll
    for (int i = 0; i < 4; ++i)
      af[i] = *(const i32x4*)&sA[(wm + 16 * i + l16) * 64 + quad * 16];
#pragma unroll
    for (int j = 0; j < 4; ++j)
      bg[j] = *(const i32x4*)&sB[(wn + 16 * j + l16) * 64 + quad * 16];
#pragma unroll
    for (int i = 0; i < 4; ++i)
#pragma unroll
      for (int j = 0; j < 4; ++j)
        iacc[i][j] = __builtin_amdgcn_mfma_i32_16x16x64_i8(af[i], bg[j], iacc[i][j], 0, 0, 0);
  }

#pragma unroll
  for (int j = 0; j < 4; ++j) {
    const int coll = wn + 16 * j + l16;
    const long long col = bn + coll;
    const float bv = bias[col];
    const float cw = sc1[coll];
#pragma unroll
    for (int i = 0; i < 4; ++i) {
      const int rowb = wm + 16 * i + quad * 4;
      const long long row0 = bm + rowb;
#pragma unroll
      for (int r = 0; r < 4; ++r) {
        float v = (float)iacc[i][j][r] * sc0[rowb + r] * cw + bv;
        if (RELU) v = fmaxf(v, 0.f);
        C[(row0 + r) * (long long)N + col] = f2bf(v);
      }
    }
  }
}

// ---------------- graph boundaries ----------------
__global__ void bounds_k(const int* __restrict__ batch, int* __restrict__ gstart, int n, int G) {
  int g = blockIdx.x * blockDim.x + threadIdx.x;
  if (g > G) return;
  int lo = 0, hi = n;
  while (lo < hi) {
    int mid = (lo + hi) >> 1;
    if (batch[mid] < g) lo = mid + 1; else hi = mid;
  }
  gstart[g] = lo;
}

// ---------------- segment max pool ----------------
__global__ void segmax_k(const unsigned short* __restrict__ h2b, const int* __restrict__ gstart,
                         float* __restrict__ pooled) {
  int g = blockIdx.x;
  int c = blockIdx.y * 256 + threadIdx.x;
  int i0 = gstart[g], i1 = gstart[g + 1];
  float m = -3.4e38f;
  for (int i = i0; i < i1; ++i) m = fmaxf(m, bf2f(h2b[(size_t)i * D2 + c]));
  if (i0 >= i1) m = 0.f;
  pooled[(size_t)g * D2 + c] = m;
}

// ---------------- MLP head (fp32) ----------------
__global__ void head1_k(const float* __restrict__ pooled, const float* __restrict__ Wf1,
                        const float* __restrict__ bf1, float* __restrict__ hid) {
  int g = blockIdx.x, chunk = blockIdx.y;
  __shared__ float sp[2048];
  for (int i = threadIdx.x; i < 2048; i += 256) sp[i] = pooled[(size_t)g * 2048 + i];
  __syncthreads();
  int wave = threadIdx.x >> 6, lane = threadIdx.x & 63;
  for (int oi = wave; oi < 64; oi += 4) {
    int o = chunk * 64 + oi;
    const float4* wr = (const float4*)&Wf1[(size_t)o * 2048];
    float s = 0.f;
    for (int c = lane; c < 512; c += 64) {
      float4 wv = wr[c];
      float4 pv = *(const float4*)&sp[c * 4];
      s += wv.x * pv.x + wv.y * pv.y + wv.z * pv.z + wv.w * pv.w;
    }
    for (int off = 32; off; off >>= 1) s += __shfl_down(s, off);
    if (lane == 0) hid[(size_t)g * 1024 + o] = fmaxf(s + bf1[o], 0.f);
  }
}
__global__ void head2_k(const float* __restrict__ hid, const float* __restrict__ Wf2,
                        const float* __restrict__ bf2, float* __restrict__ out) {
  int g = blockIdx.x, t = threadIdx.x;
  __shared__ float sh[1024];
  __shared__ float red[256];
  for (int i = t; i < 1024; i += 256) sh[i] = hid[(size_t)g * 1024 + i];
  __syncthreads();
  for (int o = 0; o < 6; ++o) {
    float s = 0.f;
    for (int k = t; k < 1024; k += 256) s += sh[k] * Wf2[o * 1024 + k];
    red[t] = s;
    __syncthreads();
    for (int d = 128; d; d >>= 1) {
      if (t < d) red[t] += red[t + d];
      __syncthreads();
    }
    if (t == 0) out[g * 6 + o] = red[0] + bf2[o];
    __syncthreads();
  }
}

extern "C" void kernel_launch(void* const* d_in, const int* in_sizes, int n_in,
                              void* d_out, int out_size, void* d_ws, size_t ws_size,
                              hipStream_t stream) {
  const float* x    = (const float*)d_in[0];
  const int* ei     = (const int*)d_in[1];
  const int* batch  = (const int*)d_in[2];
  const float* W1l  = (const float*)d_in[3];
  const float* b1   = (const float*)d_in[4];
  const float* W1r  = (const float*)d_in[5];
  const float* W2l  = (const float*)d_in[6];
  const float* b2   = (const float*)d_in[7];
  const float* W2r  = (const float*)d_in[8];
  const float* Wf1  = (const float*)d_in[9];
  const float* bf1  = (const float*)d_in[10];
  const float* Wf2  = (const float*)d_in[11];
  const float* bf2  = (const float*)d_in[12];
  float* out = (float*)d_out;

  const int E = in_sizes[1] / 2;
  const int* srcp = ei;
  const int* dstp = ei + E;
  const int NB = (MP + 255) / 256;  // scan blocks

  char* w = (char*)d_ws;
  auto take = [&](size_t b) {
    void* p = (void*)w;
    w += (b + 255) & ~(size_t)255;
    return p;
  };
  char* cat1      = (char*)take((size_t)MP * KC1);        // [mean | x] int8
  char* cat2      = (char*)take((size_t)MP * KC2);        // [mean2 | h1] int8
  unsigned short* h1b = (unsigned short*)take((size_t)MP * D1 * 2);
  unsigned short* h2b = (unsigned short*)take((size_t)MP * D2 * 2);
  char* wcat1     = (char*)take((size_t)D1 * KC1);
  char* wcat2     = (char*)take((size_t)D2 * KC2);
  float* xscale   = (float*)take((size_t)MP * 4);
  float* h1scale  = (float*)take((size_t)MP * 4);
  float* swc1     = (float*)take((size_t)D1 * 4);
  float* swc2     = (float*)take((size_t)D2 * 4);
  int* deg    = (int*)take((size_t)MP * 4);
  int* off    = (int*)take((size_t)(MP + 1) * 4);
  int* bsum   = (int*)take((size_t)(NB + 1) * 4);
  int* cursor = (int*)take((size_t)MP * 4);
  int* csr    = (int*)take((size_t)E * 4);
  int* gstart = (int*)take((size_t)(NG + 1) * 4);
  float* pooled = (float*)take((size_t)NG * D2 * 4);
  float* hid    = (float*)take((size_t)NG * 1024 * 4);

  cvt_x<<<MP, 256, 0, stream>>>(x, cat1, xscale);
  wq_cat<<<D1, 256, 0, stream>>>(W1l, W1r, D0, K0, wcat1, swc1);
  wq_cat<<<D2, 256, 0, stream>>>(W2l, W2r, D1, D1, wcat2, swc2);

  zero_i<<<(MP + 255) / 256, 256, 0, stream>>>(deg, MP);
  count_k<<<(E + 255) / 256, 256, 0, stream>>>(dstp, deg, E, NN);
  scan1_k<<<NB, 256, 0, stream>>>(deg, off, bsum, MP);
  scan2_k<<<1, 256, 0, stream>>>(bsum, NB);
  scan3_k<<<NB, 256, 0, stream>>>(off, bsum, MP, NB);
  copy_i<<<(MP + 255) / 256, 256, 0, stream>>>(off, cursor, MP);
  fill_k<<<(E + 255) / 256, 256, 0, stream>>>(srcp, dstp, cursor, csr, E, NN);

  // conv1: mean half of cat1 <- agg(x half); h1 = relu(cat1 @ wcat1^T + b1)
  agg_mean_i8w<K0, KC1><<<MP / 4, 256, 0, stream>>>(cat1, xscale, off, csr);
  gemm_i8<KC1, D1, true><<<dim3(D1 / 128, MP / 128), 256, 0, stream>>>(
      cat1, wcat1, xscale, swc1, b1, h1b);

  // conv2: quantize h1 into cat2; mean2 half <- agg(h1 half); h2 = cat2 @ wcat2^T + b2
  quant_rows<<<MP, 256, 0, stream>>>(h1b, cat2, h1scale);
  agg_mean_i8w<D1, KC2><<<MP / 4, 256, 0, stream>>>(cat2, h1scale, off, csr);
  gemm_i8<KC2, D2, false><<<dim3(D2 / 128, MP / 128), 256, 0, stream>>>(
      cat2, wcat2, h1scale, swc2, b2, h2b);

  bounds_k<<<1, 128, 0, stream>>>(batch, gstart, NN, NG);
  segmax_k<<<dim3(NG, D2 / 256), 256, 0, stream>>>(h2b, gstart, pooled);
  head1_k<<<dim3(NG, 16), 256, 0, stream>>>(pooled, Wf1, bf1, hid);
  head2_k<<<NG, 256, 0, stream>>>(hid, Wf2, bf2, out);
}